// Round 1
// baseline (2570.692 us; speedup 1.0000x reference)
//
#include <hip/hip_runtime.h>
#include <math.h>

#define NB 9  // degree 8 -> 9 basis values

static constexpr int BATCH = 1024;
static constexpr int IN1   = 1024;
static constexpr int HID1  = 2048;
static constexpr int HID2  = 1024;
static constexpr int NCLS  = 1000;

// ---------------- xn = tanh(0.5*x) in f64 ----------------
__global__ __launch_bounds__(256)
void k_xn(const float* __restrict__ x, double* __restrict__ xn, int n) {
  int i = blockIdx.x * 256 + threadIdx.x;
  if (i < n) xn[i] = tanh(0.5 * (double)x[i]);
}

// ---------------- GEMM1: h1[o][b] = sum_{i,d} T_d(xn[b,i]) * cf[o,i,d] ----
// f64 accumulate. Tile 64(b) x 64(o), ISTEP=4, 256 threads, 4x4 per thread.
__global__ __launch_bounds__(256)
void k_gemm1(const double* __restrict__ xn, const float* __restrict__ cf,
             double* __restrict__ h1) {
  __shared__ double lbas[4][64][NB];   // [ii][b][d]   18432 B
  __shared__ double lcf[4][NB][65];    // [ii][d][o]   18720 B
  const int tx = threadIdx.x & 15;   // b sub-index
  const int ty = threadIdx.x >> 4;   // o sub-index
  const int b0 = blockIdx.x * 64;
  const int o0 = blockIdx.y * 64;
  double acc[4][4];
#pragma unroll
  for (int i = 0; i < 4; ++i)
#pragma unroll
    for (int j = 0; j < 4; ++j) acc[i][j] = 0.0;

  for (int i0 = 0; i0 < IN1; i0 += 4) {
    // stage xn tile and expand Chebyshev basis (64 b x 4 i)
    {
      int e = threadIdx.x;                // 256 elements exactly
      int bb = e & 63, ii = e >> 6;       // ii in [0,4)
      double v = xn[(size_t)(b0 + bb) * IN1 + i0 + ii];
      double t0 = 1.0, t1 = v;
      lbas[ii][bb][0] = t0;
      lbas[ii][bb][1] = t1;
#pragma unroll
      for (int d = 2; d < NB; ++d) {
        double t2 = 2.0 * v * t1 - t0;
        lbas[ii][bb][d] = t2;
        t0 = t1; t1 = t2;
      }
    }
    // stage coeffs slice: 64 o x 4 i x 9 d  (f32 -> f64)
    for (int e = threadIdx.x; e < 64 * 36; e += 256) {
      int oo = e / 36;
      int r  = e - oo * 36;               // r = ii*9 + d, contiguous in global
      int ii = r / NB;
      int d  = r - ii * NB;
      lcf[ii][d][oo] =
          (double)cf[(size_t)(o0 + oo) * (IN1 * NB) + (size_t)(i0 + ii) * NB + d];
    }
    __syncthreads();
#pragma unroll
    for (int ii = 0; ii < 4; ++ii) {
#pragma unroll
      for (int d = 0; d < NB; ++d) {
        double bs[4], cv[4];
#pragma unroll
        for (int r = 0; r < 4; ++r) bs[r] = lbas[ii][tx + 16 * r][d];
#pragma unroll
        for (int r = 0; r < 4; ++r) cv[r] = lcf[ii][d][ty + 16 * r];
#pragma unroll
        for (int ro = 0; ro < 4; ++ro)
#pragma unroll
          for (int rb = 0; rb < 4; ++rb)
            acc[rb][ro] = fma(bs[rb], cv[ro], acc[rb][ro]);
      }
    }
    __syncthreads();
  }
#pragma unroll
  for (int ro = 0; ro < 4; ++ro)
#pragma unroll
    for (int rb = 0; rb < 4; ++rb)
      h1[(size_t)(o0 + ty + 16 * ro) * BATCH + b0 + tx + 16 * rb] = acc[rb][ro];
}

// ---------------- BN stats per feature: A*h_raw + C >= 2.0 is the spike ----
__global__ __launch_bounds__(256)
void k_bnstats(const double* __restrict__ h, const float* __restrict__ scale,
               const float* __restrict__ gamma, const float* __restrict__ beta,
               double* __restrict__ AC, int batch) {
  const int f = blockIdx.x;
  const double* row = h + (size_t)f * batch;
  double s1 = 0.0, s2 = 0.0;
  for (int b = threadIdx.x; b < batch; b += 256) {
    double v = row[b];
    s1 += v;
    s2 = fma(v, v, s2);
  }
#pragma unroll
  for (int off = 32; off > 0; off >>= 1) {
    s1 += __shfl_down(s1, off, 64);
    s2 += __shfl_down(s2, off, 64);
  }
  __shared__ double red[8];
  const int wid = threadIdx.x >> 6;
  if ((threadIdx.x & 63) == 0) { red[wid] = s1; red[4 + wid] = s2; }
  __syncthreads();
  if (threadIdx.x == 0) {
    double S1 = red[0] + red[1] + red[2] + red[3];
    double S2 = red[4] + red[5] + red[6] + red[7];
    double m1 = S1 / batch;
    double m2 = S2 / batch;
    double sc = (double)scale[f], g = (double)gamma[f], be = (double)beta[f];
    double var = sc * sc * (m2 - m1 * m1);
    double inv = 1.0 / sqrt(var + 1e-5);
    double A = g * sc * inv;
    double C = be - g * sc * m1 * inv;
    AC[2 * f] = A;
    AC[2 * f + 1] = C;
  }
}

// ---------------- spike + transpose: s[b][f] = (A*h[f][b]+C >= 2) ----------
__global__ __launch_bounds__(256)
void k_spike_tr(const double* __restrict__ h, const double* __restrict__ AC,
                float* __restrict__ s, int batch, int F) {
  __shared__ float tile[64][65];
  __shared__ double lA[64], lC[64];
  const int b0 = blockIdx.x * 64;
  const int f0 = blockIdx.y * 64;
  const int t = threadIdx.x;
  if (t < 64) { lA[t] = AC[2 * (f0 + t)]; lC[t] = AC[2 * (f0 + t) + 1]; }
  __syncthreads();
  const int tx = t & 63, tw = t >> 6;
  for (int fo = tw; fo < 64; fo += 4) {
    double v = h[(size_t)(f0 + fo) * batch + b0 + tx];
    tile[tx][fo] = (fma(lA[fo], v, lC[fo]) >= 2.0) ? 1.0f : 0.0f;
  }
  __syncthreads();
  for (int bo = tw; bo < 64; bo += 4) {
    s[(size_t)(b0 + bo) * F + f0 + tx] = tile[bo][tx];
  }
}

// ---------------- layer-2 precompute: binary-input folding ----------------
// a2[o][i] = sum_d (T_d(tanh .5) - T_d(0)) * cf2[o,i,d];  c0[o] = sum_i dot(T(0), cf2[o,i,:])
__global__ __launch_bounds__(256)
void k_prep2(const float* __restrict__ cf2, double* __restrict__ a2,
             double* __restrict__ c0v) {
  const int o = blockIdx.x;
  double bt[NB], b0a[NB];
  {
    double tt = tanh(0.5);
    bt[0] = 1.0; bt[1] = tt;
    b0a[0] = 1.0; b0a[1] = 0.0;
#pragma unroll
    for (int d = 2; d < NB; ++d) {
      bt[d] = 2.0 * tt * bt[d - 1] - bt[d - 2];
      b0a[d] = -b0a[d - 2];
    }
  }
  double cp = 0.0;
  for (int i = threadIdx.x; i < HID1; i += 256) {
    const float* c = cf2 + ((size_t)o * HID1 + i) * NB;
    double av = 0.0, cv = 0.0;
#pragma unroll
    for (int d = 0; d < NB; ++d) {
      double cd = (double)c[d];
      av = fma(bt[d] - b0a[d], cd, av);
      cv = fma(b0a[d], cd, cv);
    }
    a2[(size_t)o * HID1 + i] = av;
    cp += cv;
  }
#pragma unroll
  for (int off = 32; off > 0; off >>= 1) cp += __shfl_down(cp, off, 64);
  __shared__ double red[4];
  if ((threadIdx.x & 63) == 0) red[threadIdx.x >> 6] = cp;
  __syncthreads();
  if (threadIdx.x == 0) c0v[o] = red[0] + red[1] + red[2] + red[3];
}

// ---------------- GEMM2: h2[o][b] = c0[o] + sum_i s1[b][i]*a2[o][i] (f64) --
// Tile 64(b) x 32(o), ISTEP=16, 256 threads, 4x2 per thread.
__global__ __launch_bounds__(256)
void k_gemm2(const float* __restrict__ s1, const double* __restrict__ a2,
             const double* __restrict__ c0v, double* __restrict__ h2) {
  __shared__ double ls[16][64];
  __shared__ double la[16][32];
  const int tx = threadIdx.x & 15;  // b
  const int ty = threadIdx.x >> 4;  // o
  const int b0 = blockIdx.x * 64;
  const int o0 = blockIdx.y * 32;
  double acc[4][2] = {{0, 0}, {0, 0}, {0, 0}, {0, 0}};
  for (int i0 = 0; i0 < HID1; i0 += 16) {
    for (int e = threadIdx.x; e < 64 * 16; e += 256) {
      int bb = e & 63, ii = e >> 6;
      ls[ii][bb] = (double)s1[(size_t)(b0 + bb) * HID1 + i0 + ii];
    }
    for (int e = threadIdx.x; e < 32 * 16; e += 256) {
      int oo = e & 31, ii = e >> 5;
      la[ii][oo] = a2[(size_t)(o0 + oo) * HID1 + i0 + ii];
    }
    __syncthreads();
#pragma unroll
    for (int ii = 0; ii < 16; ++ii) {
      double sv[4], av[2];
#pragma unroll
      for (int r = 0; r < 4; ++r) sv[r] = ls[ii][tx + 16 * r];
      av[0] = la[ii][ty];
      av[1] = la[ii][ty + 16];
#pragma unroll
      for (int ro = 0; ro < 2; ++ro)
#pragma unroll
        for (int rb = 0; rb < 4; ++rb)
          acc[rb][ro] = fma(sv[rb], av[ro], acc[rb][ro]);
    }
    __syncthreads();
  }
#pragma unroll
  for (int ro = 0; ro < 2; ++ro) {
    double c0 = c0v[o0 + ty + 16 * ro];
#pragma unroll
    for (int rb = 0; rb < 4; ++rb)
      h2[(size_t)(o0 + ty + 16 * ro) * BATCH + b0 + tx + 16 * rb] =
          acc[rb][ro] + c0;
  }
}

// ---------------- GEMM3 (f32): out[b][n] = bias[n] + sum_k s2[b][k]*w[n][k] -
// Tile 64(b) x 64(n), ISTEP=32, 256 threads, 4x4; tx indexes n for coalesced C.
__global__ __launch_bounds__(256)
void k_gemm3(const float* __restrict__ s2, const float* __restrict__ w,
             const float* __restrict__ bias, float* __restrict__ out) {
  __shared__ float lsS[32][64];
  __shared__ float lw[32][64];
  const int tx = threadIdx.x & 15;  // n
  const int ty = threadIdx.x >> 4;  // b
  const int b0 = blockIdx.x * 64;
  const int n0 = blockIdx.y * 64;
  float acc[4][4];
#pragma unroll
  for (int i = 0; i < 4; ++i)
#pragma unroll
    for (int j = 0; j < 4; ++j) acc[i][j] = 0.0f;
  for (int k0 = 0; k0 < HID2; k0 += 32) {
    for (int e = threadIdx.x; e < 64 * 32; e += 256) {
      int bb = e & 63, kk = e >> 6;
      lsS[kk][bb] = s2[(size_t)(b0 + bb) * HID2 + k0 + kk];
    }
    for (int e = threadIdx.x; e < 64 * 32; e += 256) {
      int nn = e & 63, kk = e >> 6;
      int n = n0 + nn;
      lw[kk][nn] = (n < NCLS) ? w[(size_t)n * HID2 + k0 + kk] : 0.0f;
    }
    __syncthreads();
#pragma unroll
    for (int kk = 0; kk < 32; ++kk) {
      float sv[4], wv[4];
#pragma unroll
      for (int r = 0; r < 4; ++r) sv[r] = lsS[kk][ty + 16 * r];
#pragma unroll
      for (int r = 0; r < 4; ++r) wv[r] = lw[kk][tx + 16 * r];
#pragma unroll
      for (int rb = 0; rb < 4; ++rb)
#pragma unroll
        for (int rn = 0; rn < 4; ++rn)
          acc[rb][rn] = fmaf(sv[rb], wv[rn], acc[rb][rn]);
    }
    __syncthreads();
  }
#pragma unroll
  for (int rn = 0; rn < 4; ++rn) {
    int n = n0 + tx + 16 * rn;
    if (n < NCLS) {
      float bv = bias[n];
#pragma unroll
      for (int rb = 0; rb < 4; ++rb)
        out[(size_t)(b0 + ty + 16 * rb) * NCLS + n] = acc[rb][rn] + bv;
    }
  }
}

extern "C" void kernel_launch(void* const* d_in, const int* in_sizes, int n_in,
                              void* d_out, int out_size, void* d_ws,
                              size_t ws_size, hipStream_t stream) {
  (void)in_sizes; (void)n_in; (void)out_size; (void)ws_size;
  const float* x       = (const float*)d_in[0];
  const float* coeffs1 = (const float*)d_in[1];
  const float* scale1  = (const float*)d_in[2];
  const float* gamma1  = (const float*)d_in[3];
  const float* beta1   = (const float*)d_in[4];
  const float* coeffs2 = (const float*)d_in[5];
  const float* scale2  = (const float*)d_in[6];
  const float* gamma2  = (const float*)d_in[7];
  const float* beta2   = (const float*)d_in[8];
  const float* w       = (const float*)d_in[9];
  const float* bias    = (const float*)d_in[10];

  float* out = (float*)d_out;
  float* s1  = out + (size_t)BATCH * NCLS;
  float* s2  = s1 + (size_t)BATCH * HID1;

  char* ws = (char*)d_ws;
  double* xn  = (double*)ws; ws += (size_t)BATCH * IN1 * 8;
  double* h1  = (double*)ws; ws += (size_t)HID1 * BATCH * 8;
  double* AC1 = (double*)ws; ws += (size_t)HID1 * 2 * 8;
  double* a2  = (double*)ws; ws += (size_t)HID2 * HID1 * 8;
  double* c0v = (double*)ws; ws += (size_t)HID2 * 8;
  double* h2  = (double*)ws; ws += (size_t)HID2 * BATCH * 8;
  double* AC2 = (double*)ws; ws += (size_t)HID2 * 2 * 8;

  k_xn<<<(BATCH * IN1) / 256, 256, 0, stream>>>(x, xn, BATCH * IN1);
  k_prep2<<<HID2, 256, 0, stream>>>(coeffs2, a2, c0v);
  k_gemm1<<<dim3(BATCH / 64, HID1 / 64), 256, 0, stream>>>(xn, coeffs1, h1);
  k_bnstats<<<HID1, 256, 0, stream>>>(h1, scale1, gamma1, beta1, AC1, BATCH);
  k_spike_tr<<<dim3(BATCH / 64, HID1 / 64), 256, 0, stream>>>(h1, AC1, s1,
                                                              BATCH, HID1);
  k_gemm2<<<dim3(BATCH / 64, HID2 / 32), 256, 0, stream>>>(s1, a2, c0v, h2);
  k_bnstats<<<HID2, 256, 0, stream>>>(h2, scale2, gamma2, beta2, AC2, BATCH);
  k_spike_tr<<<dim3(BATCH / 64, HID2 / 64), 256, 0, stream>>>(h2, AC2, s2,
                                                              BATCH, HID2);
  k_gemm3<<<dim3(BATCH / 64, 1024 / 64), 256, 0, stream>>>(s2, w, bias, out);
}

// Round 3
// 2547.782 us; speedup vs baseline: 1.0090x; 1.0090x over previous
//
#include <hip/hip_runtime.h>
#include <math.h>

#define NB 9  // degree 8 -> 9 basis values

static constexpr int BATCH = 1024;
static constexpr int IN1   = 1024;
static constexpr int HID1  = 2048;
static constexpr int HID2  = 1024;
static constexpr int NCLS  = 1000;
static constexpr int K1    = IN1 * NB;  // 9216

typedef double double4v __attribute__((ext_vector_type(4)));

// ---------------- xnT[i][b] = tanh(0.5*x[b][i]) in f64 (transposed) -------
__global__ __launch_bounds__(256)
void k_xnT(const float* __restrict__ x, double* __restrict__ xnT) {
  const int i = blockIdx.x;
  const int b = blockIdx.y * 256 + threadIdx.x;
  xnT[(size_t)i * BATCH + b] = tanh(0.5 * (double)x[(size_t)b * IN1 + i]);
}

// ---------------- probe: discover f64 MFMA D-fragment mapping -------------
// A[i][k] = i + 17k (lane = i + 16k), B[k][j] = j^2 + 3k (lane = j + 16k).
// D[i][j] = 4ij^2 + 18i + 102j^2 + 714 (exact integers, f64-exact).
// flag=0: D at (lane,reg) is D[4*(lane>>4)+reg][lane&15]   (standard)
// flag=1: transposed; flag=2: neither -> VALU fallback takes over.
__global__ void k_probe(int* __restrict__ flag) {
  const int l = threadIdx.x;
  const int c = l & 15, h = l >> 4;
  double a = (double)(c + 17 * h);
  double b = (double)(c * c + 3 * h);
  double4v acc = {0.0, 0.0, 0.0, 0.0};
  acc = __builtin_amdgcn_mfma_f64_16x16x4f64(a, b, acc, 0, 0, 0);
  bool m1 = true, m2 = true;
#pragma unroll
  for (int r = 0; r < 4; ++r) {
    double v = acc[r];
    double i1 = (double)(4 * h + r), j1 = (double)c;
    double p1 = 4.0 * i1 * j1 * j1 + 18.0 * i1 + 102.0 * j1 * j1 + 714.0;
    double i2 = (double)c, j2 = (double)(4 * h + r);
    double p2 = 4.0 * i2 * j2 * j2 + 18.0 * i2 + 102.0 * j2 * j2 + 714.0;
    m1 = m1 && (v == p1);
    m2 = m2 && (v == p2);
  }
  unsigned long long b1 = __ballot(m1), b2 = __ballot(m2);
  if (l == 0)
    flag[0] = (b1 == ~0ull) ? 0 : ((b2 == ~0ull) ? 1 : 2);
}

// ---------------- GEMM1 via f64 MFMA: h1[o][b] = sum_{i,d} T_d * cf -------
// Tile 64o x 64b, 4 waves (each 32o x 32b = 2x2 frags), K-chunk 4i*9d = 36.
__global__ __launch_bounds__(256)
void k_gemm1_mfma(const double* __restrict__ xnT, const float* __restrict__ cf,
                  const int* __restrict__ flag, double* __restrict__ h1) {
  const int fl = flag[0];
  if (fl == 2) return;  // VALU fallback will do the work
  __shared__ double lA[36][66];  // [k][o] padded: +2 breaks 4-group aliasing
  __shared__ double lB[36][66];  // [k][b]
  const int tid  = threadIdx.x;
  const int lane = tid & 63;
  const int w    = tid >> 6;
  const int wo   = (w & 1) * 32;
  const int wb   = (w >> 1) * 32;
  const int o0   = blockIdx.y * 64;
  const int b0   = blockIdx.x * 64;
  const int l15  = lane & 15;
  const int l4   = lane >> 4;

  double4v acc[2][2];
#pragma unroll
  for (int m = 0; m < 2; ++m)
#pragma unroll
    for (int n = 0; n < 2; ++n) acc[m][n] = double4v{0.0, 0.0, 0.0, 0.0};

  for (int ic = 0; ic < 256; ++ic) {
    const int i0 = ic * 4;
    // stage B: expand Chebyshev basis for 4 i x 64 b (one elem per thread)
    {
      const int bb = tid & 63, ii = tid >> 6;  // ii in [0,4)
      double v = xnT[(size_t)(i0 + ii) * BATCH + b0 + bb];
      double t0 = 1.0, t1 = v;
      lB[ii * NB + 0][bb] = t0;
      lB[ii * NB + 1][bb] = t1;
#pragma unroll
      for (int d = 2; d < NB; ++d) {
        double t2 = 2.0 * v * t1 - t0;
        lB[ii * NB + d][bb] = t2;
        t0 = t1; t1 = t2;
      }
    }
    // stage A: cf slice 64 o x 36 k (f32 -> f64); k = ii*9+d contiguous
    for (int e = tid; e < 64 * 36; e += 256) {
      int oo = e / 36, r = e - oo * 36;
      lA[r][oo] = (double)cf[(size_t)(o0 + oo) * K1 + (size_t)i0 * NB + r];
    }
    __syncthreads();
#pragma unroll
    for (int k4 = 0; k4 < 9; ++k4) {
      double a[2], b[2];
#pragma unroll
      for (int m = 0; m < 2; ++m) a[m] = lA[k4 * 4 + l4][wo + m * 16 + l15];
#pragma unroll
      for (int n = 0; n < 2; ++n) b[n] = lB[k4 * 4 + l4][wb + n * 16 + l15];
#pragma unroll
      for (int m = 0; m < 2; ++m)
#pragma unroll
        for (int n = 0; n < 2; ++n)
          acc[m][n] =
              __builtin_amdgcn_mfma_f64_16x16x4f64(a[m], b[n], acc[m][n], 0, 0, 0);
    }
    __syncthreads();
  }
  if (fl == 0) {
    // D at (lane, reg j): row = 4*l4 + j, col = l15
#pragma unroll
    for (int m = 0; m < 2; ++m)
#pragma unroll
      for (int n = 0; n < 2; ++n) {
        int o = o0 + wo + m * 16 + 4 * l4;
        int b = b0 + wb + n * 16 + l15;
#pragma unroll
        for (int j = 0; j < 4; ++j)
          h1[(size_t)(o + j) * BATCH + b] = acc[m][n][j];
      }
  } else {
    // transposed mapping: row = l15, col = 4*l4 + j
#pragma unroll
    for (int m = 0; m < 2; ++m)
#pragma unroll
      for (int n = 0; n < 2; ++n) {
        int o = o0 + wo + m * 16 + l15;
        int b = b0 + wb + n * 16 + 4 * l4;
#pragma unroll
        for (int j = 0; j < 4; ++j)
          h1[(size_t)o * BATCH + b + j] = acc[m][n][j];
      }
  }
}

// ---------------- GEMM1 VALU fallback (round-0 proven; runs iff flag==2) --
__global__ __launch_bounds__(256)
void k_gemm1_valu(const double* __restrict__ xnT, const float* __restrict__ cf,
                  const int* __restrict__ flag, double* __restrict__ h1) {
  if (flag[0] != 2) return;
  __shared__ double lbas[4][64][NB];
  __shared__ double lcf[4][NB][65];
  const int tx = threadIdx.x & 15;   // b sub-index
  const int ty = threadIdx.x >> 4;   // o sub-index
  const int b0 = blockIdx.x * 64;
  const int o0 = blockIdx.y * 64;
  double acc[4][4];
#pragma unroll
  for (int i = 0; i < 4; ++i)
#pragma unroll
    for (int j = 0; j < 4; ++j) acc[i][j] = 0.0;

  for (int i0 = 0; i0 < IN1; i0 += 4) {
    {
      int e = threadIdx.x;
      int bb = e & 63, ii = e >> 6;
      double v = xnT[(size_t)(i0 + ii) * BATCH + b0 + bb];
      double t0 = 1.0, t1 = v;
      lbas[ii][bb][0] = t0;
      lbas[ii][bb][1] = t1;
#pragma unroll
      for (int d = 2; d < NB; ++d) {
        double t2 = 2.0 * v * t1 - t0;
        lbas[ii][bb][d] = t2;
        t0 = t1; t1 = t2;
      }
    }
    for (int e = threadIdx.x; e < 64 * 36; e += 256) {
      int oo = e / 36;
      int r  = e - oo * 36;
      int ii = r / NB;
      int d  = r - ii * NB;
      lcf[ii][d][oo] =
          (double)cf[(size_t)(o0 + oo) * K1 + (size_t)(i0 + ii) * NB + d];
    }
    __syncthreads();
#pragma unroll
    for (int ii = 0; ii < 4; ++ii) {
#pragma unroll
      for (int d = 0; d < NB; ++d) {
        double bs[4], cv[4];
#pragma unroll
        for (int r = 0; r < 4; ++r) bs[r] = lbas[ii][tx + 16 * r][d];
#pragma unroll
        for (int r = 0; r < 4; ++r) cv[r] = lcf[ii][d][ty + 16 * r];
#pragma unroll
        for (int ro = 0; ro < 4; ++ro)
#pragma unroll
          for (int rb = 0; rb < 4; ++rb)
            acc[rb][ro] = fma(bs[rb], cv[ro], acc[rb][ro]);
      }
    }
    __syncthreads();
  }
#pragma unroll
  for (int ro = 0; ro < 4; ++ro)
#pragma unroll
    for (int rb = 0; rb < 4; ++rb)
      h1[(size_t)(o0 + ty + 16 * ro) * BATCH + b0 + tx + 16 * rb] = acc[rb][ro];
}

// ---------------- BN stats per feature: A*h_raw + C >= 2.0 is the spike ----
__global__ __launch_bounds__(256)
void k_bnstats(const double* __restrict__ h, const float* __restrict__ scale,
               const float* __restrict__ gamma, const float* __restrict__ beta,
               double* __restrict__ AC, int batch) {
  const int f = blockIdx.x;
  const double* row = h + (size_t)f * batch;
  double s1 = 0.0, s2 = 0.0;
  for (int b = threadIdx.x; b < batch; b += 256) {
    double v = row[b];
    s1 += v;
    s2 = fma(v, v, s2);
  }
#pragma unroll
  for (int off = 32; off > 0; off >>= 1) {
    s1 += __shfl_down(s1, off, 64);
    s2 += __shfl_down(s2, off, 64);
  }
  __shared__ double red[8];
  const int wid = threadIdx.x >> 6;
  if ((threadIdx.x & 63) == 0) { red[wid] = s1; red[4 + wid] = s2; }
  __syncthreads();
  if (threadIdx.x == 0) {
    double S1 = red[0] + red[1] + red[2] + red[3];
    double S2 = red[4] + red[5] + red[6] + red[7];
    double m1 = S1 / batch;
    double m2 = S2 / batch;
    double sc = (double)scale[f], g = (double)gamma[f], be = (double)beta[f];
    double var = sc * sc * (m2 - m1 * m1);
    double inv = 1.0 / sqrt(var + 1e-5);
    double A = g * sc * inv;
    double C = be - g * sc * m1 * inv;
    AC[2 * f] = A;
    AC[2 * f + 1] = C;
  }
}

// ---------------- spike + transpose: s[b][f] = (A*h[f][b]+C >= 2) ----------
__global__ __launch_bounds__(256)
void k_spike_tr(const double* __restrict__ h, const double* __restrict__ AC,
                float* __restrict__ s, int batch, int F) {
  __shared__ float tile[64][65];
  __shared__ double lA[64], lC[64];
  const int b0 = blockIdx.x * 64;
  const int f0 = blockIdx.y * 64;
  const int t = threadIdx.x;
  if (t < 64) { lA[t] = AC[2 * (f0 + t)]; lC[t] = AC[2 * (f0 + t) + 1]; }
  __syncthreads();
  const int tx = t & 63, tw = t >> 6;
  for (int fo = tw; fo < 64; fo += 4) {
    double v = h[(size_t)(f0 + fo) * batch + b0 + tx];
    tile[tx][fo] = (fma(lA[fo], v, lC[fo]) >= 2.0) ? 1.0f : 0.0f;
  }
  __syncthreads();
  for (int bo = tw; bo < 64; bo += 4) {
    s[(size_t)(b0 + bo) * F + f0 + tx] = tile[bo][tx];
  }
}

// ---------------- layer-2 precompute: binary-input folding ----------------
__global__ __launch_bounds__(256)
void k_prep2(const float* __restrict__ cf2, double* __restrict__ a2,
             double* __restrict__ c0v) {
  const int o = blockIdx.x;
  double bt[NB], b0a[NB];
  {
    double tt = tanh(0.5);
    bt[0] = 1.0; bt[1] = tt;
    b0a[0] = 1.0; b0a[1] = 0.0;
#pragma unroll
    for (int d = 2; d < NB; ++d) {
      bt[d] = 2.0 * tt * bt[d - 1] - bt[d - 2];
      b0a[d] = -b0a[d - 2];
    }
  }
  double cp = 0.0;
  for (int i = threadIdx.x; i < HID1; i += 256) {
    const float* c = cf2 + ((size_t)o * HID1 + i) * NB;
    double av = 0.0, cv = 0.0;
#pragma unroll
    for (int d = 0; d < NB; ++d) {
      double cd = (double)c[d];
      av = fma(bt[d] - b0a[d], cd, av);
      cv = fma(b0a[d], cd, cv);
    }
    a2[(size_t)o * HID1 + i] = av;
    cp += cv;
  }
#pragma unroll
  for (int off = 32; off > 0; off >>= 1) cp += __shfl_down(cp, off, 64);
  __shared__ double red[4];
  if ((threadIdx.x & 63) == 0) red[threadIdx.x >> 6] = cp;
  __syncthreads();
  if (threadIdx.x == 0) c0v[o] = red[0] + red[1] + red[2] + red[3];
}

// ---------------- GEMM2: h2[o][b] = c0[o] + sum_i s1[b][i]*a2[o][i] (f64) --
__global__ __launch_bounds__(256)
void k_gemm2(const float* __restrict__ s1, const double* __restrict__ a2,
             const double* __restrict__ c0v, double* __restrict__ h2) {
  __shared__ double ls[16][64];
  __shared__ double la[16][32];
  const int tx = threadIdx.x & 15;  // b
  const int ty = threadIdx.x >> 4;  // o
  const int b0 = blockIdx.x * 64;
  const int o0 = blockIdx.y * 32;
  double acc[4][2] = {{0, 0}, {0, 0}, {0, 0}, {0, 0}};
  for (int i0 = 0; i0 < HID1; i0 += 16) {
    for (int e = threadIdx.x; e < 64 * 16; e += 256) {
      int bb = e & 63, ii = e >> 6;
      ls[ii][bb] = (double)s1[(size_t)(b0 + bb) * HID1 + i0 + ii];
    }
    for (int e = threadIdx.x; e < 32 * 16; e += 256) {
      int oo = e & 31, ii = e >> 5;
      la[ii][oo] = a2[(size_t)(o0 + oo) * HID1 + i0 + ii];
    }
    __syncthreads();
#pragma unroll
    for (int ii = 0; ii < 16; ++ii) {
      double sv[4], av[2];
#pragma unroll
      for (int r = 0; r < 4; ++r) sv[r] = ls[ii][tx + 16 * r];
      av[0] = la[ii][ty];
      av[1] = la[ii][ty + 16];
#pragma unroll
      for (int ro = 0; ro < 2; ++ro)
#pragma unroll
        for (int rb = 0; rb < 4; ++rb)
          acc[rb][ro] = fma(sv[rb], av[ro], acc[rb][ro]);
    }
    __syncthreads();
  }
#pragma unroll
  for (int ro = 0; ro < 2; ++ro) {
    double c0 = c0v[o0 + ty + 16 * ro];
#pragma unroll
    for (int rb = 0; rb < 4; ++rb)
      h2[(size_t)(o0 + ty + 16 * ro) * BATCH + b0 + tx + 16 * rb] =
          acc[rb][ro] + c0;
  }
}

// ---------------- GEMM3 (f32): out[b][n] = bias[n] + sum_k s2[b][k]*w[n][k] -
__global__ __launch_bounds__(256)
void k_gemm3(const float* __restrict__ s2, const float* __restrict__ w,
             const float* __restrict__ bias, float* __restrict__ out) {
  __shared__ float lsS[32][64];
  __shared__ float lw[32][64];
  const int tx = threadIdx.x & 15;  // n
  const int ty = threadIdx.x >> 4;  // b
  const int b0 = blockIdx.x * 64;
  const int n0 = blockIdx.y * 64;
  float acc[4][4];
#pragma unroll
  for (int i = 0; i < 4; ++i)
#pragma unroll
    for (int j = 0; j < 4; ++j) acc[i][j] = 0.0f;
  for (int k0 = 0; k0 < HID2; k0 += 32) {
    for (int e = threadIdx.x; e < 64 * 32; e += 256) {
      int bb = e & 63, kk = e >> 6;
      lsS[kk][bb] = s2[(size_t)(b0 + bb) * HID2 + k0 + kk];
    }
    for (int e = threadIdx.x; e < 64 * 32; e += 256) {
      int nn = e & 63, kk = e >> 6;
      int n = n0 + nn;
      lw[kk][nn] = (n < NCLS) ? w[(size_t)n * HID2 + k0 + kk] : 0.0f;
    }
    __syncthreads();
#pragma unroll
    for (int kk = 0; kk < 32; ++kk) {
      float sv[4], wv[4];
#pragma unroll
      for (int r = 0; r < 4; ++r) sv[r] = lsS[kk][ty + 16 * r];
#pragma unroll
      for (int r = 0; r < 4; ++r) wv[r] = lw[kk][tx + 16 * r];
#pragma unroll
      for (int rb = 0; rb < 4; ++rb)
#pragma unroll
        for (int rn = 0; rn < 4; ++rn)
          acc[rb][rn] = fmaf(sv[rb], wv[rn], acc[rb][rn]);
    }
    __syncthreads();
  }
#pragma unroll
  for (int rn = 0; rn < 4; ++rn) {
    int n = n0 + tx + 16 * rn;
    if (n < NCLS) {
      float bv = bias[n];
#pragma unroll
      for (int rb = 0; rb < 4; ++rb)
        out[(size_t)(b0 + ty + 16 * rb) * NCLS + n] = acc[rb][rn] + bv;
    }
  }
}

extern "C" void kernel_launch(void* const* d_in, const int* in_sizes, int n_in,
                              void* d_out, int out_size, void* d_ws,
                              size_t ws_size, hipStream_t stream) {
  (void)in_sizes; (void)n_in; (void)out_size; (void)ws_size;
  const float* x       = (const float*)d_in[0];
  const float* coeffs1 = (const float*)d_in[1];
  const float* scale1  = (const float*)d_in[2];
  const float* gamma1  = (const float*)d_in[3];
  const float* beta1   = (const float*)d_in[4];
  const float* coeffs2 = (const float*)d_in[5];
  const float* scale2  = (const float*)d_in[6];
  const float* gamma2  = (const float*)d_in[7];
  const float* beta2   = (const float*)d_in[8];
  const float* w       = (const float*)d_in[9];
  const float* bias    = (const float*)d_in[10];

  float* out = (float*)d_out;
  float* s1  = out + (size_t)BATCH * NCLS;
  float* s2  = s1 + (size_t)BATCH * HID1;

  char* ws = (char*)d_ws;
  int*    flag = (int*)ws;   ws += 16;
  double* xnT  = (double*)ws; ws += (size_t)IN1 * BATCH * 8;
  double* h1   = (double*)ws; ws += (size_t)HID1 * BATCH * 8;
  double* AC1  = (double*)ws; ws += (size_t)HID1 * 2 * 8;
  double* a2   = (double*)ws; ws += (size_t)HID2 * HID1 * 8;
  double* c0v  = (double*)ws; ws += (size_t)HID2 * 8;
  double* h2   = (double*)ws; ws += (size_t)HID2 * BATCH * 8;
  double* AC2  = (double*)ws; ws += (size_t)HID2 * 2 * 8;

  k_xnT<<<dim3(IN1, BATCH / 256), 256, 0, stream>>>(x, xnT);
  k_probe<<<1, 64, 0, stream>>>(flag);
  k_prep2<<<HID2, 256, 0, stream>>>(coeffs2, a2, c0v);
  k_gemm1_mfma<<<dim3(BATCH / 64, HID1 / 64), 256, 0, stream>>>(xnT, coeffs1,
                                                                flag, h1);
  k_gemm1_valu<<<dim3(BATCH / 64, HID1 / 64), 256, 0, stream>>>(xnT, coeffs1,
                                                                flag, h1);
  k_bnstats<<<HID1, 256, 0, stream>>>(h1, scale1, gamma1, beta1, AC1, BATCH);
  k_spike_tr<<<dim3(BATCH / 64, HID1 / 64), 256, 0, stream>>>(h1, AC1, s1,
                                                              BATCH, HID1);
  k_gemm2<<<dim3(BATCH / 64, HID2 / 32), 256, 0, stream>>>(s1, a2, c0v, h2);
  k_bnstats<<<HID2, 256, 0, stream>>>(h2, scale2, gamma2, beta2, AC2, BATCH);
  k_spike_tr<<<dim3(BATCH / 64, HID2 / 64), 256, 0, stream>>>(h2, AC2, s2,
                                                              BATCH, HID2);
  k_gemm3<<<dim3(BATCH / 64, 1024 / 64), 256, 0, stream>>>(s2, w, bias, out);
}

// Round 4
// 2212.966 us; speedup vs baseline: 1.1616x; 1.1513x over previous
//
#include <hip/hip_runtime.h>
#include <math.h>

#define NB 9  // degree 8 -> 9 basis values

static constexpr int BATCH = 1024;
static constexpr int IN1   = 1024;
static constexpr int HID1  = 2048;
static constexpr int HID2  = 1024;
static constexpr int NCLS  = 1000;
static constexpr int K1    = IN1 * NB;  // 9216

typedef double double4v __attribute__((ext_vector_type(4)));

// ---------------- xnT[i][b] = tanh(0.5*x[b][i]) in f64 (transposed) -------
__global__ __launch_bounds__(256)
void k_xnT(const float* __restrict__ x, double* __restrict__ xnT) {
  const int i = blockIdx.x;
  const int b = blockIdx.y * 256 + threadIdx.x;
  xnT[(size_t)i * BATCH + b] = tanh(0.5 * (double)x[(size_t)b * IN1 + i]);
}

// ---------------- probe: discover f64 MFMA operand + D layouts ------------
// Lane value fed as A: fA(l); as B: gB(l). Exact small integers in f64.
// A-layout ao: 0: lane = i + 16k ; 1: lane = 4i + k        (A is 16x4)
// B-layout bo: 0: lane = j + 16k ; 1: lane = 4j + k        (B is 4x16)
// D-layout dopt: 0: row=4*(l>>4)+r, col=l&15 ; 1: transpose of 0
//                2: row=(l>>4)+4*r, col=l&15 ; 3: transpose of 2
// flag = ao*8 + bo*4 + dopt, or 16 if nothing matches (-> VALU fallback).
__device__ __forceinline__ double fA(int l) {
  return (double)((l & 15) + 17 * (l >> 4));
}
__device__ __forceinline__ double gB(int l) {
  return (double)((l & 15) * (l & 15) + 3 * (l >> 4));
}

__global__ void k_probe(int* __restrict__ flag) {
  const int l = threadIdx.x;
  double4v acc = {0.0, 0.0, 0.0, 0.0};
  acc = __builtin_amdgcn_mfma_f64_16x16x4f64(fA(l), gB(l), acc, 0, 0, 0);
  bool ok[16];
#pragma unroll
  for (int c = 0; c < 16; ++c) ok[c] = true;
  for (int dopt = 0; dopt < 4; ++dopt) {
    for (int r = 0; r < 4; ++r) {
      int q = (dopt < 2) ? (4 * (l >> 4) + r) : ((l >> 4) + 4 * r);
      int i = (dopt == 0 || dopt == 2) ? q : (l & 15);
      int j = (dopt == 0 || dopt == 2) ? (l & 15) : q;
      double v = acc[r];
      for (int ao = 0; ao < 2; ++ao)
        for (int bo = 0; bo < 2; ++bo) {
          double p = 0.0;
          for (int k = 0; k < 4; ++k) {
            int la = ao ? (4 * i + k) : (i + 16 * k);
            int lb = bo ? (4 * j + k) : (j + 16 * k);
            p += fA(la) * gB(lb);
          }
          if (v != p) ok[ao * 8 + bo * 4 + dopt] = false;
        }
    }
  }
  int res = 16;
  for (int c = 15; c >= 0; --c)
    if (__ballot(ok[c]) == ~0ull) res = c;
  if (l == 0) flag[0] = res;
}

// ---------------- GEMM1 via f64 MFMA: h1[o][b] = sum_{i,d} T_d * cf -------
// Tile 64o x 64b, 4 waves (each 32o x 32b = 2x2 frags), K-chunk 4i*9d = 36.
__global__ __launch_bounds__(256)
void k_gemm1_mfma(const double* __restrict__ xnT, const float* __restrict__ cf,
                  const int* __restrict__ flag, double* __restrict__ h1) {
  const int fl = flag[0];
  if (fl >= 16) return;  // VALU fallback will do the work
  const int ao = fl >> 3, bo = (fl >> 2) & 1, dopt = fl & 3;
  __shared__ double lA[36][66];  // [k][o] padded
  __shared__ double lB[36][66];  // [k][b]
  const int tid  = threadIdx.x;
  const int lane = tid & 63;
  const int w    = tid >> 6;
  const int wo   = (w & 1) * 32;
  const int wb   = (w >> 1) * 32;
  const int o0   = blockIdx.y * 64;
  const int b0   = blockIdx.x * 64;
  const int l15  = lane & 15;
  const int l4   = lane >> 4;
  // operand fragment indices per discovered layouts
  const int am = ao ? (lane >> 2) : l15;
  const int ak = ao ? (lane & 3)  : l4;
  const int bn = bo ? (lane >> 2) : l15;
  const int bk = bo ? (lane & 3)  : l4;

  double4v acc[2][2];
#pragma unroll
  for (int m = 0; m < 2; ++m)
#pragma unroll
    for (int n = 0; n < 2; ++n) acc[m][n] = double4v{0.0, 0.0, 0.0, 0.0};

  for (int ic = 0; ic < 256; ++ic) {
    const int i0 = ic * 4;
    // stage B: expand Chebyshev basis for 4 i x 64 b (one elem per thread)
    {
      const int bb = tid & 63, ii = tid >> 6;  // ii in [0,4)
      double v = xnT[(size_t)(i0 + ii) * BATCH + b0 + bb];
      double t0 = 1.0, t1 = v;
      lB[ii * NB + 0][bb] = t0;
      lB[ii * NB + 1][bb] = t1;
#pragma unroll
      for (int d = 2; d < NB; ++d) {
        double t2 = 2.0 * v * t1 - t0;
        lB[ii * NB + d][bb] = t2;
        t0 = t1; t1 = t2;
      }
    }
    // stage A: cf slice 64 o x 36 k (f32 -> f64); k = ii*9+d contiguous
    for (int e = tid; e < 64 * 36; e += 256) {
      int oo = e / 36, r = e - oo * 36;
      lA[r][oo] = (double)cf[(size_t)(o0 + oo) * K1 + (size_t)i0 * NB + r];
    }
    __syncthreads();
#pragma unroll
    for (int k4 = 0; k4 < 9; ++k4) {
      double a[2], b[2];
#pragma unroll
      for (int m = 0; m < 2; ++m) a[m] = lA[k4 * 4 + ak][wo + m * 16 + am];
#pragma unroll
      for (int n = 0; n < 2; ++n) b[n] = lB[k4 * 4 + bk][wb + n * 16 + bn];
#pragma unroll
      for (int m = 0; m < 2; ++m)
#pragma unroll
        for (int n = 0; n < 2; ++n)
          acc[m][n] =
              __builtin_amdgcn_mfma_f64_16x16x4f64(a[m], b[n], acc[m][n], 0, 0, 0);
    }
    __syncthreads();
  }
  // write D per discovered layout (branches are wave-uniform)
#pragma unroll
  for (int m = 0; m < 2; ++m)
#pragma unroll
    for (int n = 0; n < 2; ++n) {
      const int ob = o0 + wo + m * 16;
      const int bb = b0 + wb + n * 16;
      if (dopt == 0) {
        int o = ob + 4 * l4, b = bb + l15;
#pragma unroll
        for (int j = 0; j < 4; ++j)
          h1[(size_t)(o + j) * BATCH + b] = acc[m][n][j];
      } else if (dopt == 1) {
        int o = ob + l15, b = bb + 4 * l4;
#pragma unroll
        for (int j = 0; j < 4; ++j)
          h1[(size_t)o * BATCH + b + j] = acc[m][n][j];
      } else if (dopt == 2) {
        int o = ob + l4, b = bb + l15;
#pragma unroll
        for (int j = 0; j < 4; ++j)
          h1[(size_t)(o + 4 * j) * BATCH + b] = acc[m][n][j];
      } else {
        int o = ob + l15, b = bb + l4;
#pragma unroll
        for (int j = 0; j < 4; ++j)
          h1[(size_t)o * BATCH + b + 4 * j] = acc[m][n][j];
      }
    }
}

// ---------------- GEMM1 VALU fallback (proven; runs iff flag==16) ---------
__global__ __launch_bounds__(256)
void k_gemm1_valu(const double* __restrict__ xnT, const float* __restrict__ cf,
                  const int* __restrict__ flag, double* __restrict__ h1) {
  if (flag[0] != 16) return;
  __shared__ double lbas[4][64][NB];
  __shared__ double lcf[4][NB][65];
  const int tx = threadIdx.x & 15;   // b sub-index
  const int ty = threadIdx.x >> 4;   // o sub-index
  const int b0 = blockIdx.x * 64;
  const int o0 = blockIdx.y * 64;
  double acc[4][4];
#pragma unroll
  for (int i = 0; i < 4; ++i)
#pragma unroll
    for (int j = 0; j < 4; ++j) acc[i][j] = 0.0;

  for (int i0 = 0; i0 < IN1; i0 += 4) {
    {
      int e = threadIdx.x;
      int bb = e & 63, ii = e >> 6;
      double v = xnT[(size_t)(i0 + ii) * BATCH + b0 + bb];
      double t0 = 1.0, t1 = v;
      lbas[ii][bb][0] = t0;
      lbas[ii][bb][1] = t1;
#pragma unroll
      for (int d = 2; d < NB; ++d) {
        double t2 = 2.0 * v * t1 - t0;
        lbas[ii][bb][d] = t2;
        t0 = t1; t1 = t2;
      }
    }
    for (int e = threadIdx.x; e < 64 * 36; e += 256) {
      int oo = e / 36;
      int r  = e - oo * 36;
      int ii = r / NB;
      int d  = r - ii * NB;
      lcf[ii][d][oo] =
          (double)cf[(size_t)(o0 + oo) * K1 + (size_t)(i0 + ii) * NB + d];
    }
    __syncthreads();
#pragma unroll
    for (int ii = 0; ii < 4; ++ii) {
#pragma unroll
      for (int d = 0; d < NB; ++d) {
        double bs[4], cv[4];
#pragma unroll
        for (int r = 0; r < 4; ++r) bs[r] = lbas[ii][tx + 16 * r][d];
#pragma unroll
        for (int r = 0; r < 4; ++r) cv[r] = lcf[ii][d][ty + 16 * r];
#pragma unroll
        for (int ro = 0; ro < 4; ++ro)
#pragma unroll
          for (int rb = 0; rb < 4; ++rb)
            acc[rb][ro] = fma(bs[rb], cv[ro], acc[rb][ro]);
      }
    }
    __syncthreads();
  }
#pragma unroll
  for (int ro = 0; ro < 4; ++ro)
#pragma unroll
    for (int rb = 0; rb < 4; ++rb)
      h1[(size_t)(o0 + ty + 16 * ro) * BATCH + b0 + tx + 16 * rb] = acc[rb][ro];
}

// ---------------- BN stats per feature: A*h_raw + C >= 2.0 is the spike ----
__global__ __launch_bounds__(256)
void k_bnstats(const double* __restrict__ h, const float* __restrict__ scale,
               const float* __restrict__ gamma, const float* __restrict__ beta,
               double* __restrict__ AC, int batch) {
  const int f = blockIdx.x;
  const double* row = h + (size_t)f * batch;
  double s1 = 0.0, s2 = 0.0;
  for (int b = threadIdx.x; b < batch; b += 256) {
    double v = row[b];
    s1 += v;
    s2 = fma(v, v, s2);
  }
#pragma unroll
  for (int off = 32; off > 0; off >>= 1) {
    s1 += __shfl_down(s1, off, 64);
    s2 += __shfl_down(s2, off, 64);
  }
  __shared__ double red[8];
  const int wid = threadIdx.x >> 6;
  if ((threadIdx.x & 63) == 0) { red[wid] = s1; red[4 + wid] = s2; }
  __syncthreads();
  if (threadIdx.x == 0) {
    double S1 = red[0] + red[1] + red[2] + red[3];
    double S2 = red[4] + red[5] + red[6] + red[7];
    double m1 = S1 / batch;
    double m2 = S2 / batch;
    double sc = (double)scale[f], g = (double)gamma[f], be = (double)beta[f];
    double var = sc * sc * (m2 - m1 * m1);
    double inv = 1.0 / sqrt(var + 1e-5);
    double A = g * sc * inv;
    double C = be - g * sc * m1 * inv;
    AC[2 * f] = A;
    AC[2 * f + 1] = C;
  }
}

// ---------------- spike + transpose: s[b][f] = (A*h[f][b]+C >= 2) ----------
__global__ __launch_bounds__(256)
void k_spike_tr(const double* __restrict__ h, const double* __restrict__ AC,
                float* __restrict__ s, int batch, int F) {
  __shared__ float tile[64][65];
  __shared__ double lA[64], lC[64];
  const int b0 = blockIdx.x * 64;
  const int f0 = blockIdx.y * 64;
  const int t = threadIdx.x;
  if (t < 64) { lA[t] = AC[2 * (f0 + t)]; lC[t] = AC[2 * (f0 + t) + 1]; }
  __syncthreads();
  const int tx = t & 63, tw = t >> 6;
  for (int fo = tw; fo < 64; fo += 4) {
    double v = h[(size_t)(f0 + fo) * batch + b0 + tx];
    tile[tx][fo] = (fma(lA[fo], v, lC[fo]) >= 2.0) ? 1.0f : 0.0f;
  }
  __syncthreads();
  for (int bo = tw; bo < 64; bo += 4) {
    s[(size_t)(b0 + bo) * F + f0 + tx] = tile[bo][tx];
  }
}

// ---------------- layer-2 precompute: binary-input folding ----------------
__global__ __launch_bounds__(256)
void k_prep2(const float* __restrict__ cf2, double* __restrict__ a2,
             double* __restrict__ c0v) {
  const int o = blockIdx.x;
  double bt[NB], b0a[NB];
  {
    double tt = tanh(0.5);
    bt[0] = 1.0; bt[1] = tt;
    b0a[0] = 1.0; b0a[1] = 0.0;
#pragma unroll
    for (int d = 2; d < NB; ++d) {
      bt[d] = 2.0 * tt * bt[d - 1] - bt[d - 2];
      b0a[d] = -b0a[d - 2];
    }
  }
  double cp = 0.0;
  for (int i = threadIdx.x; i < HID1; i += 256) {
    const float* c = cf2 + ((size_t)o * HID1 + i) * NB;
    double av = 0.0, cv = 0.0;
#pragma unroll
    for (int d = 0; d < NB; ++d) {
      double cd = (double)c[d];
      av = fma(bt[d] - b0a[d], cd, av);
      cv = fma(b0a[d], cd, cv);
    }
    a2[(size_t)o * HID1 + i] = av;
    cp += cv;
  }
#pragma unroll
  for (int off = 32; off > 0; off >>= 1) cp += __shfl_down(cp, off, 64);
  __shared__ double red[4];
  if ((threadIdx.x & 63) == 0) red[threadIdx.x >> 6] = cp;
  __syncthreads();
  if (threadIdx.x == 0) c0v[o] = red[0] + red[1] + red[2] + red[3];
}

// ---------------- GEMM2: h2[o][b] = c0[o] + sum_i s1[b][i]*a2[o][i] (f64) --
__global__ __launch_bounds__(256)
void k_gemm2(const float* __restrict__ s1, const double* __restrict__ a2,
             const double* __restrict__ c0v, double* __restrict__ h2) {
  __shared__ double ls[16][64];
  __shared__ double la[16][32];
  const int tx = threadIdx.x & 15;  // b
  const int ty = threadIdx.x >> 4;  // o
  const int b0 = blockIdx.x * 64;
  const int o0 = blockIdx.y * 32;
  double acc[4][2] = {{0, 0}, {0, 0}, {0, 0}, {0, 0}};
  for (int i0 = 0; i0 < HID1; i0 += 16) {
    for (int e = threadIdx.x; e < 64 * 16; e += 256) {
      int bb = e & 63, ii = e >> 6;
      ls[ii][bb] = (double)s1[(size_t)(b0 + bb) * HID1 + i0 + ii];
    }
    for (int e = threadIdx.x; e < 32 * 16; e += 256) {
      int oo = e & 31, ii = e >> 5;
      la[ii][oo] = a2[(size_t)(o0 + oo) * HID1 + i0 + ii];
    }
    __syncthreads();
#pragma unroll
    for (int ii = 0; ii < 16; ++ii) {
      double sv[4], av[2];
#pragma unroll
      for (int r = 0; r < 4; ++r) sv[r] = ls[ii][tx + 16 * r];
      av[0] = la[ii][ty];
      av[1] = la[ii][ty + 16];
#pragma unroll
      for (int ro = 0; ro < 2; ++ro)
#pragma unroll
        for (int rb = 0; rb < 4; ++rb)
          acc[rb][ro] = fma(sv[rb], av[ro], acc[rb][ro]);
    }
    __syncthreads();
  }
#pragma unroll
  for (int ro = 0; ro < 2; ++ro) {
    double c0 = c0v[o0 + ty + 16 * ro];
#pragma unroll
    for (int rb = 0; rb < 4; ++rb)
      h2[(size_t)(o0 + ty + 16 * ro) * BATCH + b0 + tx + 16 * rb] =
          acc[rb][ro] + c0;
  }
}

// ---------------- GEMM3 (f32): out[b][n] = bias[n] + sum_k s2[b][k]*w[n][k] -
__global__ __launch_bounds__(256)
void k_gemm3(const float* __restrict__ s2, const float* __restrict__ w,
             const float* __restrict__ bias, float* __restrict__ out) {
  __shared__ float lsS[32][64];
  __shared__ float lw[32][64];
  const int tx = threadIdx.x & 15;  // n
  const int ty = threadIdx.x >> 4;  // b
  const int b0 = blockIdx.x * 64;
  const int n0 = blockIdx.y * 64;
  float acc[4][4];
#pragma unroll
  for (int i = 0; i < 4; ++i)
#pragma unroll
    for (int j = 0; j < 4; ++j) acc[i][j] = 0.0f;
  for (int k0 = 0; k0 < HID2; k0 += 32) {
    for (int e = threadIdx.x; e < 64 * 32; e += 256) {
      int bb = e & 63, kk = e >> 6;
      lsS[kk][bb] = s2[(size_t)(b0 + bb) * HID2 + k0 + kk];
    }
    for (int e = threadIdx.x; e < 64 * 32; e += 256) {
      int nn = e & 63, kk = e >> 6;
      int n = n0 + nn;
      lw[kk][nn] = (n < NCLS) ? w[(size_t)n * HID2 + k0 + kk] : 0.0f;
    }
    __syncthreads();
#pragma unroll
    for (int kk = 0; kk < 32; ++kk) {
      float sv[4], wv[4];
#pragma unroll
      for (int r = 0; r < 4; ++r) sv[r] = lsS[kk][ty + 16 * r];
#pragma unroll
      for (int r = 0; r < 4; ++r) wv[r] = lw[kk][tx + 16 * r];
#pragma unroll
      for (int rb = 0; rb < 4; ++rb)
#pragma unroll
        for (int rn = 0; rn < 4; ++rn)
          acc[rb][rn] = fmaf(sv[rb], wv[rn], acc[rb][rn]);
    }
    __syncthreads();
  }
#pragma unroll
  for (int rn = 0; rn < 4; ++rn) {
    int n = n0 + tx + 16 * rn;
    if (n < NCLS) {
      float bv = bias[n];
#pragma unroll
      for (int rb = 0; rb < 4; ++rb)
        out[(size_t)(b0 + ty + 16 * rb) * NCLS + n] = acc[rb][rn] + bv;
    }
  }
}

extern "C" void kernel_launch(void* const* d_in, const int* in_sizes, int n_in,
                              void* d_out, int out_size, void* d_ws,
                              size_t ws_size, hipStream_t stream) {
  (void)in_sizes; (void)n_in; (void)out_size; (void)ws_size;
  const float* x       = (const float*)d_in[0];
  const float* coeffs1 = (const float*)d_in[1];
  const float* scale1  = (const float*)d_in[2];
  const float* gamma1  = (const float*)d_in[3];
  const float* beta1   = (const float*)d_in[4];
  const float* coeffs2 = (const float*)d_in[5];
  const float* scale2  = (const float*)d_in[6];
  const float* gamma2  = (const float*)d_in[7];
  const float* beta2   = (const float*)d_in[8];
  const float* w       = (const float*)d_in[9];
  const float* bias    = (const float*)d_in[10];

  float* out = (float*)d_out;
  float* s1  = out + (size_t)BATCH * NCLS;
  float* s2  = s1 + (size_t)BATCH * HID1;

  char* ws = (char*)d_ws;
  int*    flag = (int*)ws;   ws += 16;
  double* xnT  = (double*)ws; ws += (size_t)IN1 * BATCH * 8;
  double* h1   = (double*)ws; ws += (size_t)HID1 * BATCH * 8;
  double* AC1  = (double*)ws; ws += (size_t)HID1 * 2 * 8;
  double* a2   = (double*)ws; ws += (size_t)HID2 * HID1 * 8;
  double* c0v  = (double*)ws; ws += (size_t)HID2 * 8;
  double* h2   = (double*)ws; ws += (size_t)HID2 * BATCH * 8;
  double* AC2  = (double*)ws; ws += (size_t)HID2 * 2 * 8;

  k_xnT<<<dim3(IN1, BATCH / 256), 256, 0, stream>>>(x, xnT);
  k_probe<<<1, 64, 0, stream>>>(flag);
  k_prep2<<<HID2, 256, 0, stream>>>(coeffs2, a2, c0v);
  k_gemm1_mfma<<<dim3(BATCH / 64, HID1 / 64), 256, 0, stream>>>(xnT, coeffs1,
                                                                flag, h1);
  k_gemm1_valu<<<dim3(BATCH / 64, HID1 / 64), 256, 0, stream>>>(xnT, coeffs1,
                                                                flag, h1);
  k_bnstats<<<HID1, 256, 0, stream>>>(h1, scale1, gamma1, beta1, AC1, BATCH);
  k_spike_tr<<<dim3(BATCH / 64, HID1 / 64), 256, 0, stream>>>(h1, AC1, s1,
                                                              BATCH, HID1);
  k_gemm2<<<dim3(BATCH / 64, HID2 / 32), 256, 0, stream>>>(s1, a2, c0v, h2);
  k_bnstats<<<HID2, 256, 0, stream>>>(h2, scale2, gamma2, beta2, AC2, BATCH);
  k_spike_tr<<<dim3(BATCH / 64, HID2 / 64), 256, 0, stream>>>(h2, AC2, s2,
                                                              BATCH, HID2);
  k_gemm3<<<dim3(BATCH / 64, 1024 / 64), 256, 0, stream>>>(s2, w, bias, out);
}

// Round 5
// 1281.180 us; speedup vs baseline: 2.0065x; 1.7273x over previous
//
#include <hip/hip_runtime.h>
#include <math.h>

#define NB 9  // degree 8 -> 9 basis values

static constexpr int BATCH = 1024;
static constexpr int IN1   = 1024;
static constexpr int HID1  = 2048;
static constexpr int HID2  = 1024;
static constexpr int NCLS  = 1000;
static constexpr int K1    = IN1 * NB;  // 9216

typedef double double4v __attribute__((ext_vector_type(4)));

// ---------------- xnT[i][b] = tanh(0.5*x[b][i]) in f64 (transposed) -------
__global__ __launch_bounds__(256)
void k_xnT(const float* __restrict__ x, double* __restrict__ xnT) {
  const int i = blockIdx.x;
  const int b = blockIdx.y * 256 + threadIdx.x;
  xnT[(size_t)i * BATCH + b] = tanh(0.5 * (double)x[(size_t)b * IN1 + i]);
}

// ---------------- probe: discover f64 MFMA operand + D layouts ------------
// flag = ao*8 + bo*4 + dopt, or 16 if nothing matches (-> VALU fallback).
__device__ __forceinline__ double fA(int l) {
  return (double)((l & 15) + 17 * (l >> 4));
}
__device__ __forceinline__ double gB(int l) {
  return (double)((l & 15) * (l & 15) + 3 * (l >> 4));
}

__global__ void k_probe(int* __restrict__ flag) {
  const int l = threadIdx.x;
  double4v acc = {0.0, 0.0, 0.0, 0.0};
  acc = __builtin_amdgcn_mfma_f64_16x16x4f64(fA(l), gB(l), acc, 0, 0, 0);
  bool ok[16];
#pragma unroll
  for (int c = 0; c < 16; ++c) ok[c] = true;
  for (int dopt = 0; dopt < 4; ++dopt) {
    for (int r = 0; r < 4; ++r) {
      int q = (dopt < 2) ? (4 * (l >> 4) + r) : ((l >> 4) + 4 * r);
      int i = (dopt == 0 || dopt == 2) ? q : (l & 15);
      int j = (dopt == 0 || dopt == 2) ? (l & 15) : q;
      double v = acc[r];
      for (int ao = 0; ao < 2; ++ao)
        for (int bo = 0; bo < 2; ++bo) {
          double p = 0.0;
          for (int k = 0; k < 4; ++k) {
            int la = ao ? (4 * i + k) : (i + 16 * k);
            int lb = bo ? (4 * j + k) : (j + 16 * k);
            p += fA(la) * gB(lb);
          }
          if (v != p) ok[ao * 8 + bo * 4 + dopt] = false;
        }
    }
  }
  int res = 16;
  for (int c = 15; c >= 0; --c)
    if (__ballot(ok[c]) == ~0ull) res = c;
  if (l == 0) flag[0] = res;
}

// ---------------- GEMM1 via f64 MFMA, 2-phase pipelined -------------------
// h1[o][b] = sum_{i,d} T_d(xn[b,i]) * cf[o,i,d]
// Tile 128o x 64b, K-chunk = 4i*9d = 36. 4 waves, each 64o x 32b (4x2 frags).
// Double-buffered LDS, one barrier/iter; cf kept f32 in LDS, cvt at read.
__global__ __launch_bounds__(256)
void k_gemm1_mfma(const double* __restrict__ xnT, const float* __restrict__ cf,
                  const int* __restrict__ flag, double* __restrict__ h1) {
  const int fl = flag[0];
  if (fl >= 16) return;  // VALU fallback will do the work
  const int ao = fl >> 3, bo = (fl >> 2) & 1, dopt = fl & 3;
  __shared__ float  lA[2][36][130];  // [buf][k][o]  37.4 KB
  __shared__ double lB[2][36][66];   // [buf][k][b]  38.0 KB
  const int tid  = threadIdx.x;
  const int lane = tid & 63;
  const int w    = tid >> 6;
  const int wo   = (w & 1) * 64;
  const int wb   = (w >> 1) * 32;
  const int o0   = blockIdx.y * 128;
  const int b0   = blockIdx.x * 64;
  const int l15  = lane & 15;
  const int l4   = lane >> 4;
  const int am = ao ? (lane >> 2) : l15;
  const int ak = ao ? (lane & 3)  : l4;
  const int bn = bo ? (lane >> 2) : l15;
  const int bk = bo ? (lane & 3)  : l4;
  // staging ownership: A: 2 threads/row, 18 k each; B: 1 thread per (ii,b)
  const int soo = tid >> 1, sk0 = (tid & 1) * 18;
  const int sbb = tid & 63, sii = tid >> 6;

  double4v acc[4][2];
#pragma unroll
  for (int m = 0; m < 4; ++m)
#pragma unroll
    for (int n = 0; n < 2; ++n) acc[m][n] = double4v{0.0, 0.0, 0.0, 0.0};

  const float* abase = cf + (size_t)(o0 + soo) * K1 + sk0;
  float2 creg[9];
  double xv;
  // prologue: load tile 0 into regs
  {
    const float2* src = (const float2*)abase;
#pragma unroll
    for (int q = 0; q < 9; ++q) creg[q] = src[q];
    xv = xnT[(size_t)sii * BATCH + b0 + sbb];
  }
  int cur = 0;
  for (int ic = 0; ic < 256; ++ic) {
    // ---- store tile ic (from regs) into LDS[cur] ----
#pragma unroll
    for (int q = 0; q < 9; ++q) {
      lA[cur][sk0 + 2 * q][soo]     = creg[q].x;
      lA[cur][sk0 + 2 * q + 1][soo] = creg[q].y;
    }
    {
      double t0 = 1.0, t1 = xv;
      lB[cur][sii * NB + 0][sbb] = t0;
      lB[cur][sii * NB + 1][sbb] = t1;
#pragma unroll
      for (int d = 2; d < NB; ++d) {
        double t2 = 2.0 * xv * t1 - t0;
        lB[cur][sii * NB + d][sbb] = t2;
        t0 = t1; t1 = t2;
      }
    }
    __syncthreads();
    // ---- issue prefetch of tile ic+1 (hides under MFMA below) ----
    if (ic < 255) {
      const int i0 = (ic + 1) * 4;
      const float2* src = (const float2*)(abase + (size_t)i0 * NB);
#pragma unroll
      for (int q = 0; q < 9; ++q) creg[q] = src[q];
      xv = xnT[(size_t)(i0 + sii) * BATCH + b0 + sbb];
    }
    // ---- MFMA on LDS[cur]: 9 k4-steps x 8 MFMA ----
#pragma unroll
    for (int k4 = 0; k4 < 9; ++k4) {
      double a[4], b[2];
#pragma unroll
      for (int m = 0; m < 4; ++m)
        a[m] = (double)lA[cur][k4 * 4 + ak][wo + m * 16 + am];
#pragma unroll
      for (int n = 0; n < 2; ++n)
        b[n] = lB[cur][k4 * 4 + bk][wb + n * 16 + bn];
#pragma unroll
      for (int m = 0; m < 4; ++m)
#pragma unroll
        for (int n = 0; n < 2; ++n)
          acc[m][n] =
              __builtin_amdgcn_mfma_f64_16x16x4f64(a[m], b[n], acc[m][n], 0, 0, 0);
    }
    cur ^= 1;
  }
  // write D per discovered layout (wave-uniform branches)
#pragma unroll
  for (int m = 0; m < 4; ++m)
#pragma unroll
    for (int n = 0; n < 2; ++n) {
      const int ob = o0 + wo + m * 16;
      const int bb = b0 + wb + n * 16;
      if (dopt == 0) {
        int o = ob + 4 * l4, b = bb + l15;
#pragma unroll
        for (int j = 0; j < 4; ++j)
          h1[(size_t)(o + j) * BATCH + b] = acc[m][n][j];
      } else if (dopt == 1) {
        int o = ob + l15, b = bb + 4 * l4;
#pragma unroll
        for (int j = 0; j < 4; ++j)
          h1[(size_t)o * BATCH + b + j] = acc[m][n][j];
      } else if (dopt == 2) {
        int o = ob + l4, b = bb + l15;
#pragma unroll
        for (int j = 0; j < 4; ++j)
          h1[(size_t)(o + 4 * j) * BATCH + b] = acc[m][n][j];
      } else {
        int o = ob + l15, b = bb + l4;
#pragma unroll
        for (int j = 0; j < 4; ++j)
          h1[(size_t)o * BATCH + b + 4 * j] = acc[m][n][j];
      }
    }
}

// ---------------- GEMM1 VALU fallback (proven; runs iff flag==16) ---------
__global__ __launch_bounds__(256)
void k_gemm1_valu(const double* __restrict__ xnT, const float* __restrict__ cf,
                  const int* __restrict__ flag, double* __restrict__ h1) {
  if (flag[0] != 16) return;
  __shared__ double lbas[4][64][NB];
  __shared__ double lcf[4][NB][65];
  const int tx = threadIdx.x & 15;
  const int ty = threadIdx.x >> 4;
  const int b0 = blockIdx.x * 64;
  const int o0 = blockIdx.y * 64;
  double acc[4][4];
#pragma unroll
  for (int i = 0; i < 4; ++i)
#pragma unroll
    for (int j = 0; j < 4; ++j) acc[i][j] = 0.0;

  for (int i0 = 0; i0 < IN1; i0 += 4) {
    {
      int e = threadIdx.x;
      int bb = e & 63, ii = e >> 6;
      double v = xnT[(size_t)(i0 + ii) * BATCH + b0 + bb];
      double t0 = 1.0, t1 = v;
      lbas[ii][bb][0] = t0;
      lbas[ii][bb][1] = t1;
#pragma unroll
      for (int d = 2; d < NB; ++d) {
        double t2 = 2.0 * v * t1 - t0;
        lbas[ii][bb][d] = t2;
        t0 = t1; t1 = t2;
      }
    }
    for (int e = threadIdx.x; e < 64 * 36; e += 256) {
      int oo = e / 36;
      int r  = e - oo * 36;
      int ii = r / NB;
      int d  = r - ii * NB;
      lcf[ii][d][oo] =
          (double)cf[(size_t)(o0 + oo) * K1 + (size_t)(i0 + ii) * NB + d];
    }
    __syncthreads();
#pragma unroll
    for (int ii = 0; ii < 4; ++ii) {
#pragma unroll
      for (int d = 0; d < NB; ++d) {
        double bs[4], cv[4];
#pragma unroll
        for (int r = 0; r < 4; ++r) bs[r] = lbas[ii][tx + 16 * r][d];
#pragma unroll
        for (int r = 0; r < 4; ++r) cv[r] = lcf[ii][d][ty + 16 * r];
#pragma unroll
        for (int ro = 0; ro < 4; ++ro)
#pragma unroll
          for (int rb = 0; rb < 4; ++rb)
            acc[rb][ro] = fma(bs[rb], cv[ro], acc[rb][ro]);
      }
    }
    __syncthreads();
  }
#pragma unroll
  for (int ro = 0; ro < 4; ++ro)
#pragma unroll
    for (int rb = 0; rb < 4; ++rb)
      h1[(size_t)(o0 + ty + 16 * ro) * BATCH + b0 + tx + 16 * rb] = acc[rb][ro];
}

// ---------------- BN stats per feature: A*h_raw + C >= 2.0 is the spike ----
__global__ __launch_bounds__(256)
void k_bnstats(const double* __restrict__ h, const float* __restrict__ scale,
               const float* __restrict__ gamma, const float* __restrict__ beta,
               double* __restrict__ AC, int batch) {
  const int f = blockIdx.x;
  const double* row = h + (size_t)f * batch;
  double s1 = 0.0, s2 = 0.0;
  for (int b = threadIdx.x; b < batch; b += 256) {
    double v = row[b];
    s1 += v;
    s2 = fma(v, v, s2);
  }
#pragma unroll
  for (int off = 32; off > 0; off >>= 1) {
    s1 += __shfl_down(s1, off, 64);
    s2 += __shfl_down(s2, off, 64);
  }
  __shared__ double red[8];
  const int wid = threadIdx.x >> 6;
  if ((threadIdx.x & 63) == 0) { red[wid] = s1; red[4 + wid] = s2; }
  __syncthreads();
  if (threadIdx.x == 0) {
    double S1 = red[0] + red[1] + red[2] + red[3];
    double S2 = red[4] + red[5] + red[6] + red[7];
    double m1 = S1 / batch;
    double m2 = S2 / batch;
    double sc = (double)scale[f], g = (double)gamma[f], be = (double)beta[f];
    double var = sc * sc * (m2 - m1 * m1);
    double inv = 1.0 / sqrt(var + 1e-5);
    double A = g * sc * inv;
    double C = be - g * sc * m1 * inv;
    AC[2 * f] = A;
    AC[2 * f + 1] = C;
  }
}

// ---------------- spike + transpose: s[b][f] = (A*h[f][b]+C >= 2) ----------
__global__ __launch_bounds__(256)
void k_spike_tr(const double* __restrict__ h, const double* __restrict__ AC,
                float* __restrict__ s, int batch, int F) {
  __shared__ float tile[64][65];
  __shared__ double lA[64], lC[64];
  const int b0 = blockIdx.x * 64;
  const int f0 = blockIdx.y * 64;
  const int t = threadIdx.x;
  if (t < 64) { lA[t] = AC[2 * (f0 + t)]; lC[t] = AC[2 * (f0 + t) + 1]; }
  __syncthreads();
  const int tx = t & 63, tw = t >> 6;
  for (int fo = tw; fo < 64; fo += 4) {
    double v = h[(size_t)(f0 + fo) * batch + b0 + tx];
    tile[tx][fo] = (fma(lA[fo], v, lC[fo]) >= 2.0) ? 1.0f : 0.0f;
  }
  __syncthreads();
  for (int bo = tw; bo < 64; bo += 4) {
    s[(size_t)(b0 + bo) * F + f0 + tx] = tile[bo][tx];
  }
}

// ---------------- layer-2 precompute: binary-input folding ----------------
__global__ __launch_bounds__(256)
void k_prep2(const float* __restrict__ cf2, double* __restrict__ a2,
             double* __restrict__ c0v) {
  const int o = blockIdx.x;
  double bt[NB], b0a[NB];
  {
    double tt = tanh(0.5);
    bt[0] = 1.0; bt[1] = tt;
    b0a[0] = 1.0; b0a[1] = 0.0;
#pragma unroll
    for (int d = 2; d < NB; ++d) {
      bt[d] = 2.0 * tt * bt[d - 1] - bt[d - 2];
      b0a[d] = -b0a[d - 2];
    }
  }
  double cp = 0.0;
  for (int i = threadIdx.x; i < HID1; i += 256) {
    const float* c = cf2 + ((size_t)o * HID1 + i) * NB;
    double av = 0.0, cv = 0.0;
#pragma unroll
    for (int d = 0; d < NB; ++d) {
      double cd = (double)c[d];
      av = fma(bt[d] - b0a[d], cd, av);
      cv = fma(b0a[d], cd, cv);
    }
    a2[(size_t)o * HID1 + i] = av;
    cp += cv;
  }
#pragma unroll
  for (int off = 32; off > 0; off >>= 1) cp += __shfl_down(cp, off, 64);
  __shared__ double red[4];
  if ((threadIdx.x & 63) == 0) red[threadIdx.x >> 6] = cp;
  __syncthreads();
  if (threadIdx.x == 0) c0v[o] = red[0] + red[1] + red[2] + red[3];
}

// ---------------- GEMM2 via f64 MFMA, 2-phase pipelined -------------------
// h2[o][b] = c0[o] + sum_i s1[b][i]*a2[o][i].  Tile 64o x 64b, K-chunk 32.
__global__ __launch_bounds__(256)
void k_gemm2_mfma(const float* __restrict__ s1, const double* __restrict__ a2,
                  const double* __restrict__ c0v, const int* __restrict__ flag,
                  double* __restrict__ h2) {
  const int fl = flag[0];
  if (fl >= 16) return;
  const int ao = fl >> 3, bo = (fl >> 2) & 1, dopt = fl & 3;
  __shared__ double lA[2][32][66];  // a2 tile  33.8 KB
  __shared__ float  lB[2][32][66];  // s1 tile  16.9 KB
  const int tid  = threadIdx.x;
  const int lane = tid & 63;
  const int w    = tid >> 6;
  const int wo   = (w & 1) * 32;
  const int wb   = (w >> 1) * 32;
  const int o0   = blockIdx.y * 64;
  const int b0   = blockIdx.x * 64;
  const int l15  = lane & 15;
  const int l4   = lane >> 4;
  const int am = ao ? (lane >> 2) : l15;
  const int ak = ao ? (lane & 3)  : l4;
  const int bn = bo ? (lane >> 2) : l15;
  const int bk = bo ? (lane & 3)  : l4;
  const int srow = tid >> 2, sk = (tid & 3) * 8;  // 4 threads/row, 8 k each

  double4v acc[2][2];
#pragma unroll
  for (int m = 0; m < 2; ++m)
#pragma unroll
    for (int n = 0; n < 2; ++n) acc[m][n] = double4v{0.0, 0.0, 0.0, 0.0};

  const double* Abase = a2 + (size_t)(o0 + srow) * HID1 + sk;
  const float*  Bbase = s1 + (size_t)(b0 + srow) * HID1 + sk;
  double areg[8];
  float  breg[8];
#pragma unroll
  for (int q = 0; q < 8; ++q) areg[q] = Abase[q];
#pragma unroll
  for (int q = 0; q < 8; ++q) breg[q] = Bbase[q];

  int cur = 0;
  for (int t = 0; t < HID1 / 32; ++t) {
#pragma unroll
    for (int q = 0; q < 8; ++q) lA[cur][sk + q][srow] = areg[q];
#pragma unroll
    for (int q = 0; q < 8; ++q) lB[cur][sk + q][srow] = breg[q];
    __syncthreads();
    if (t < HID1 / 32 - 1) {
      const int i0 = (t + 1) * 32;
#pragma unroll
      for (int q = 0; q < 8; ++q) areg[q] = Abase[i0 + q];
#pragma unroll
      for (int q = 0; q < 8; ++q) breg[q] = Bbase[i0 + q];
    }
#pragma unroll
    for (int k4 = 0; k4 < 8; ++k4) {
      double a[2], b[2];
#pragma unroll
      for (int m = 0; m < 2; ++m)
        a[m] = lA[cur][k4 * 4 + ak][wo + m * 16 + am];
#pragma unroll
      for (int n = 0; n < 2; ++n)
        b[n] = (double)lB[cur][k4 * 4 + bk][wb + n * 16 + bn];
#pragma unroll
      for (int m = 0; m < 2; ++m)
#pragma unroll
        for (int n = 0; n < 2; ++n)
          acc[m][n] =
              __builtin_amdgcn_mfma_f64_16x16x4f64(a[m], b[n], acc[m][n], 0, 0, 0);
    }
    cur ^= 1;
  }
#pragma unroll
  for (int m = 0; m < 2; ++m)
#pragma unroll
    for (int n = 0; n < 2; ++n) {
      const int ob = o0 + wo + m * 16;
      const int bb = b0 + wb + n * 16;
      if (dopt == 0) {
        int o = ob + 4 * l4, b = bb + l15;
#pragma unroll
        for (int j = 0; j < 4; ++j)
          h2[(size_t)(o + j) * BATCH + b] = acc[m][n][j] + c0v[o + j];
      } else if (dopt == 1) {
        int o = ob + l15, b = bb + 4 * l4;
        double c0 = c0v[o];
#pragma unroll
        for (int j = 0; j < 4; ++j)
          h2[(size_t)o * BATCH + b + j] = acc[m][n][j] + c0;
      } else if (dopt == 2) {
        int o = ob + l4, b = bb + l15;
#pragma unroll
        for (int j = 0; j < 4; ++j)
          h2[(size_t)(o + 4 * j) * BATCH + b] = acc[m][n][j] + c0v[o + 4 * j];
      } else {
        int o = ob + l15, b = bb + l4;
        double c0 = c0v[o];
#pragma unroll
        for (int j = 0; j < 4; ++j)
          h2[(size_t)o * BATCH + b + 4 * j] = acc[m][n][j] + c0;
      }
    }
}

// ---------------- GEMM2 VALU fallback (proven; runs iff flag==16) ---------
__global__ __launch_bounds__(256)
void k_gemm2_valu(const float* __restrict__ s1, const double* __restrict__ a2,
                  const double* __restrict__ c0v, const int* __restrict__ flag,
                  double* __restrict__ h2) {
  if (flag[0] != 16) return;
  __shared__ double ls[16][64];
  __shared__ double la[16][32];
  const int tx = threadIdx.x & 15;
  const int ty = threadIdx.x >> 4;
  const int b0 = blockIdx.x * 64;
  const int o0 = blockIdx.y * 32;
  double acc[4][2] = {{0, 0}, {0, 0}, {0, 0}, {0, 0}};
  for (int i0 = 0; i0 < HID1; i0 += 16) {
    for (int e = threadIdx.x; e < 64 * 16; e += 256) {
      int bb = e & 63, ii = e >> 6;
      ls[ii][bb] = (double)s1[(size_t)(b0 + bb) * HID1 + i0 + ii];
    }
    for (int e = threadIdx.x; e < 32 * 16; e += 256) {
      int oo = e & 31, ii = e >> 5;
      la[ii][oo] = a2[(size_t)(o0 + oo) * HID1 + i0 + ii];
    }
    __syncthreads();
#pragma unroll
    for (int ii = 0; ii < 16; ++ii) {
      double sv[4], av[2];
#pragma unroll
      for (int r = 0; r < 4; ++r) sv[r] = ls[ii][tx + 16 * r];
      av[0] = la[ii][ty];
      av[1] = la[ii][ty + 16];
#pragma unroll
      for (int ro = 0; ro < 2; ++ro)
#pragma unroll
        for (int rb = 0; rb < 4; ++rb)
          acc[rb][ro] = fma(sv[rb], av[ro], acc[rb][ro]);
    }
    __syncthreads();
  }
#pragma unroll
  for (int ro = 0; ro < 2; ++ro) {
    double c0 = c0v[o0 + ty + 16 * ro];
#pragma unroll
    for (int rb = 0; rb < 4; ++rb)
      h2[(size_t)(o0 + ty + 16 * ro) * BATCH + b0 + tx + 16 * rb] =
          acc[rb][ro] + c0;
  }
}

// ---------------- GEMM3 (f32): out[b][n] = bias[n] + sum_k s2[b][k]*w[n][k] -
__global__ __launch_bounds__(256)
void k_gemm3(const float* __restrict__ s2, const float* __restrict__ w,
             const float* __restrict__ bias, float* __restrict__ out) {
  __shared__ float lsS[32][64];
  __shared__ float lw[32][64];
  const int tx = threadIdx.x & 15;  // n
  const int ty = threadIdx.x >> 4;  // b
  const int b0 = blockIdx.x * 64;
  const int n0 = blockIdx.y * 64;
  float acc[4][4];
#pragma unroll
  for (int i = 0; i < 4; ++i)
#pragma unroll
    for (int j = 0; j < 4; ++j) acc[i][j] = 0.0f;
  for (int k0 = 0; k0 < HID2; k0 += 32) {
    for (int e = threadIdx.x; e < 64 * 32; e += 256) {
      int bb = e & 63, kk = e >> 6;
      lsS[kk][bb] = s2[(size_t)(b0 + bb) * HID2 + k0 + kk];
    }
    for (int e = threadIdx.x; e < 64 * 32; e += 256) {
      int nn = e & 63, kk = e >> 6;
      int n = n0 + nn;
      lw[kk][nn] = (n < NCLS) ? w[(size_t)n * HID2 + k0 + kk] : 0.0f;
    }
    __syncthreads();
#pragma unroll
    for (int kk = 0; kk < 32; ++kk) {
      float sv[4], wv[4];
#pragma unroll
      for (int r = 0; r < 4; ++r) sv[r] = lsS[kk][ty + 16 * r];
#pragma unroll
      for (int r = 0; r < 4; ++r) wv[r] = lw[kk][tx + 16 * r];
#pragma unroll
      for (int rb = 0; rb < 4; ++rb)
#pragma unroll
        for (int rn = 0; rn < 4; ++rn)
          acc[rb][rn] = fmaf(sv[rb], wv[rn], acc[rb][rn]);
    }
    __syncthreads();
  }
#pragma unroll
  for (int rn = 0; rn < 4; ++rn) {
    int n = n0 + tx + 16 * rn;
    if (n < NCLS) {
      float bv = bias[n];
#pragma unroll
      for (int rb = 0; rb < 4; ++rb)
        out[(size_t)(b0 + ty + 16 * rb) * NCLS + n] = acc[rb][rn] + bv;
    }
  }
}

extern "C" void kernel_launch(void* const* d_in, const int* in_sizes, int n_in,
                              void* d_out, int out_size, void* d_ws,
                              size_t ws_size, hipStream_t stream) {
  (void)in_sizes; (void)n_in; (void)out_size; (void)ws_size;
  const float* x       = (const float*)d_in[0];
  const float* coeffs1 = (const float*)d_in[1];
  const float* scale1  = (const float*)d_in[2];
  const float* gamma1  = (const float*)d_in[3];
  const float* beta1   = (const float*)d_in[4];
  const float* coeffs2 = (const float*)d_in[5];
  const float* scale2  = (const float*)d_in[6];
  const float* gamma2  = (const float*)d_in[7];
  const float* beta2   = (const float*)d_in[8];
  const float* w       = (const float*)d_in[9];
  const float* bias    = (const float*)d_in[10];

  float* out = (float*)d_out;
  float* s1  = out + (size_t)BATCH * NCLS;
  float* s2  = s1 + (size_t)BATCH * HID1;

  char* ws = (char*)d_ws;
  int*    flag = (int*)ws;   ws += 16;
  double* xnT  = (double*)ws; ws += (size_t)IN1 * BATCH * 8;
  double* h1   = (double*)ws; ws += (size_t)HID1 * BATCH * 8;
  double* AC1  = (double*)ws; ws += (size_t)HID1 * 2 * 8;
  double* a2   = (double*)ws; ws += (size_t)HID2 * HID1 * 8;
  double* c0v  = (double*)ws; ws += (size_t)HID2 * 8;
  double* h2   = (double*)ws; ws += (size_t)HID2 * BATCH * 8;
  double* AC2  = (double*)ws; ws += (size_t)HID2 * 2 * 8;

  k_xnT<<<dim3(IN1, BATCH / 256), 256, 0, stream>>>(x, xnT);
  k_probe<<<1, 64, 0, stream>>>(flag);
  k_prep2<<<HID2, 256, 0, stream>>>(coeffs2, a2, c0v);
  k_gemm1_mfma<<<dim3(BATCH / 64, HID1 / 128), 256, 0, stream>>>(xnT, coeffs1,
                                                                 flag, h1);
  k_gemm1_valu<<<dim3(BATCH / 64, HID1 / 64), 256, 0, stream>>>(xnT, coeffs1,
                                                                flag, h1);
  k_bnstats<<<HID1, 256, 0, stream>>>(h1, scale1, gamma1, beta1, AC1, BATCH);
  k_spike_tr<<<dim3(BATCH / 64, HID1 / 64), 256, 0, stream>>>(h1, AC1, s1,
                                                              BATCH, HID1);
  k_gemm2_mfma<<<dim3(BATCH / 64, HID2 / 64), 256, 0, stream>>>(s1, a2, c0v,
                                                                flag, h2);
  k_gemm2_valu<<<dim3(BATCH / 64, HID2 / 32), 256, 0, stream>>>(s1, a2, c0v,
                                                                flag, h2);
  k_bnstats<<<HID2, 256, 0, stream>>>(h2, scale2, gamma2, beta2, AC2, BATCH);
  k_spike_tr<<<dim3(BATCH / 64, HID2 / 64), 256, 0, stream>>>(h2, AC2, s2,
                                                              BATCH, HID2);
  k_gemm3<<<dim3(BATCH / 64, 1024 / 64), 256, 0, stream>>>(s2, w, bias, out);
}

// Round 6
// 1125.540 us; speedup vs baseline: 2.2840x; 1.1383x over previous
//
#include <hip/hip_runtime.h>
#include <math.h>

#define NB 9  // degree 8 -> 9 basis values

static constexpr int BATCH = 1024;
static constexpr int IN1   = 1024;
static constexpr int HID1  = 2048;
static constexpr int HID2  = 1024;
static constexpr int NCLS  = 1000;
static constexpr int K1    = IN1 * NB;  // 9216

typedef double double4v __attribute__((ext_vector_type(4)));

// ---------------- xnT[i][b] = tanh(0.5*x[b][i]) (tiled transpose) ---------
__global__ __launch_bounds__(256)
void k_xnT(const float* __restrict__ x, double* __restrict__ xnT) {
  __shared__ double t[32][33];
  const int i0 = blockIdx.x * 32, b0 = blockIdx.y * 32;
  const int tx = threadIdx.x & 31, ty = threadIdx.x >> 5;  // ty in [0,8)
#pragma unroll
  for (int r = 0; r < 4; ++r) {
    int bl = ty + 8 * r;
    t[tx][bl] = tanh(0.5 * (double)x[(size_t)(b0 + bl) * IN1 + i0 + tx]);
  }
  __syncthreads();
#pragma unroll
  for (int r = 0; r < 4; ++r) {
    int il = ty + 8 * r;
    xnT[(size_t)(i0 + il) * BATCH + b0 + tx] = t[il][tx];
  }
}

// ---------------- probe: discover f64 MFMA operand + D layouts ------------
__device__ __forceinline__ double fA(int l) {
  return (double)((l & 15) + 17 * (l >> 4));
}
__device__ __forceinline__ double gB(int l) {
  return (double)((l & 15) * (l & 15) + 3 * (l >> 4));
}

__global__ void k_probe(int* __restrict__ flag) {
  const int l = threadIdx.x;
  double4v acc = {0.0, 0.0, 0.0, 0.0};
  acc = __builtin_amdgcn_mfma_f64_16x16x4f64(fA(l), gB(l), acc, 0, 0, 0);
  bool ok[16];
#pragma unroll
  for (int c = 0; c < 16; ++c) ok[c] = true;
  for (int dopt = 0; dopt < 4; ++dopt) {
    for (int r = 0; r < 4; ++r) {
      int q = (dopt < 2) ? (4 * (l >> 4) + r) : ((l >> 4) + 4 * r);
      int i = (dopt == 0 || dopt == 2) ? q : (l & 15);
      int j = (dopt == 0 || dopt == 2) ? (l & 15) : q;
      double v = acc[r];
      for (int ao = 0; ao < 2; ++ao)
        for (int bo = 0; bo < 2; ++bo) {
          double p = 0.0;
          for (int k = 0; k < 4; ++k) {
            int la = ao ? (4 * i + k) : (i + 16 * k);
            int lb = bo ? (4 * j + k) : (j + 16 * k);
            p += fA(la) * gB(lb);
          }
          if (v != p) ok[ao * 8 + bo * 4 + dopt] = false;
        }
    }
  }
  int res = 16;
  for (int c = 15; c >= 0; --c)
    if (__ballot(ok[c]) == ~0ull) res = c;
  if (l == 0) flag[0] = res;
}

// ---------------- c1c[o] = sum_i cf[o,i,0]  (folded T_0 term) -------------
__global__ __launch_bounds__(64)
void k_prep1(const float* __restrict__ cf, double* __restrict__ c1c) {
  const int o = blockIdx.x;
  double s = 0.0;
  for (int i = threadIdx.x; i < IN1; i += 64)
    s += (double)cf[(size_t)o * K1 + (size_t)i * NB];
#pragma unroll
  for (int off = 32; off > 0; off >>= 1) s += __shfl_down(s, off, 64);
  if (threadIdx.x == 0) c1c[o] = s;
}

// ---------------- GEMM1 via f64 MFMA, 2-phase pipelined, d0 folded --------
// h1[o][b] = c1c[o] + sum_{i, d=1..8} T_d(xn[b,i]) * cf[o,i,d]
// Tile 128o x 32b, K-chunk = 4i*8d = 32. 4 waves, each 32o x 32b (2x2 frags).
__global__ __launch_bounds__(256)
void k_gemm1_mfma(const double* __restrict__ xnT, const float* __restrict__ cf,
                  const double* __restrict__ c1c, const int* __restrict__ flag,
                  double* __restrict__ h1) {
  const int fl = flag[0];
  if (fl >= 16) return;  // VALU fallback will do the work
  const int ao = fl >> 3, bo = (fl >> 2) & 1, dopt = fl & 3;
  __shared__ float  lA[2][32][136];  // [buf][k][o]  34816 B, stride%32==8
  __shared__ double lB[2][32][35];   // [buf][k][b]  17920 B
  const int tid  = threadIdx.x;
  const int lane = tid & 63;
  const int w    = tid >> 6;
  const int wo   = w * 32;           // 4 waves x 32 o = 128
  const int o0   = blockIdx.y * 128;
  const int b0   = blockIdx.x * 32;
  const int l15  = lane & 15;
  const int l4   = lane >> 4;
  const int am = ao ? (lane >> 2) : l15;
  const int ak = ao ? (lane & 3)  : l4;
  const int bn = bo ? (lane >> 2) : l15;
  const int bk = bo ? (lane & 3)  : l4;
  // staging: A: 2 threads/o-row, 16 k each (2 i-groups of 8 d)
  const int soo = tid >> 1, si2 = (tid & 1) * 2;  // i-offset 0 or 2
  // staging: B: threads 0..127: 4 i x 32 b
  const int sbb = tid & 31, sii = (tid >> 5) & 3;

  double4v acc[2][2];
#pragma unroll
  for (int m = 0; m < 2; ++m)
#pragma unroll
    for (int n = 0; n < 2; ++n) acc[m][n] = double4v{0.0, 0.0, 0.0, 0.0};

  const float* abase = cf + (size_t)(o0 + soo) * K1;
  float c16[16];
  double xv = 0.0;
  // prologue: load tile 0 into regs
#pragma unroll
  for (int j2 = 0; j2 < 2; ++j2)
#pragma unroll
    for (int d = 0; d < 8; ++d)
      c16[j2 * 8 + d] = abase[(size_t)(si2 + j2) * NB + 1 + d];
  if (tid < 128) xv = xnT[(size_t)sii * BATCH + b0 + sbb];

  int cur = 0;
  for (int ic = 0; ic < 256; ++ic) {
    // ---- store tile ic into LDS[cur] ----
#pragma unroll
    for (int j2 = 0; j2 < 2; ++j2)
#pragma unroll
      for (int d = 0; d < 8; ++d)
        lA[cur][si2 * 8 + j2 * 8 + d][soo] = c16[j2 * 8 + d];
    if (tid < 128) {
      double t0 = 1.0, t1 = xv;
      lB[cur][sii * 8 + 0][sbb] = t1;
#pragma unroll
      for (int d = 2; d < NB; ++d) {
        double t2 = 2.0 * xv * t1 - t0;
        lB[cur][sii * 8 + d - 1][sbb] = t2;
        t0 = t1; t1 = t2;
      }
    }
    __syncthreads();
    // ---- prefetch tile ic+1 (hides under MFMA) ----
    if (ic < 255) {
      const int i0n = (ic + 1) * 4;
#pragma unroll
      for (int j2 = 0; j2 < 2; ++j2)
#pragma unroll
        for (int d = 0; d < 8; ++d)
          c16[j2 * 8 + d] = abase[(size_t)(i0n + si2 + j2) * NB + 1 + d];
      if (tid < 128) xv = xnT[(size_t)(i0n + sii) * BATCH + b0 + sbb];
    }
    // ---- MFMA on LDS[cur]: 8 k4-steps x 4 MFMA ----
    __builtin_amdgcn_s_setprio(1);
#pragma unroll
    for (int k4 = 0; k4 < 8; ++k4) {
      double a[2], b[2];
#pragma unroll
      for (int m = 0; m < 2; ++m)
        a[m] = (double)lA[cur][k4 * 4 + ak][wo + m * 16 + am];
#pragma unroll
      for (int n = 0; n < 2; ++n)
        b[n] = lB[cur][k4 * 4 + bk][n * 16 + bn];
#pragma unroll
      for (int m = 0; m < 2; ++m)
#pragma unroll
        for (int n = 0; n < 2; ++n)
          acc[m][n] =
              __builtin_amdgcn_mfma_f64_16x16x4f64(a[m], b[n], acc[m][n], 0, 0, 0);
    }
    __builtin_amdgcn_s_setprio(0);
    cur ^= 1;
  }
  // write D per discovered layout (+ folded d0 constant)
#pragma unroll
  for (int m = 0; m < 2; ++m)
#pragma unroll
    for (int n = 0; n < 2; ++n) {
      const int ob = o0 + wo + m * 16;
      const int bb = b0 + n * 16;
      if (dopt == 0) {
        int o = ob + 4 * l4, b = bb + l15;
#pragma unroll
        for (int j = 0; j < 4; ++j)
          h1[(size_t)(o + j) * BATCH + b] = acc[m][n][j] + c1c[o + j];
      } else if (dopt == 1) {
        int o = ob + l15, b = bb + 4 * l4;
        double cc = c1c[o];
#pragma unroll
        for (int j = 0; j < 4; ++j)
          h1[(size_t)o * BATCH + b + j] = acc[m][n][j] + cc;
      } else if (dopt == 2) {
        int o = ob + l4, b = bb + l15;
#pragma unroll
        for (int j = 0; j < 4; ++j)
          h1[(size_t)(o + 4 * j) * BATCH + b] = acc[m][n][j] + c1c[o + 4 * j];
      } else {
        int o = ob + l15, b = bb + l4;
        double cc = c1c[o];
#pragma unroll
        for (int j = 0; j < 4; ++j)
          h1[(size_t)o * BATCH + b + 4 * j] = acc[m][n][j] + cc;
      }
    }
}

// ---------------- GEMM1 VALU fallback (proven; runs iff flag==16) ---------
__global__ __launch_bounds__(256)
void k_gemm1_valu(const double* __restrict__ xnT, const float* __restrict__ cf,
                  const int* __restrict__ flag, double* __restrict__ h1) {
  if (flag[0] != 16) return;
  __shared__ double lbas[4][64][NB];
  __shared__ double lcf[4][NB][65];
  const int tx = threadIdx.x & 15;
  const int ty = threadIdx.x >> 4;
  const int b0 = blockIdx.x * 64;
  const int o0 = blockIdx.y * 64;
  double acc[4][4];
#pragma unroll
  for (int i = 0; i < 4; ++i)
#pragma unroll
    for (int j = 0; j < 4; ++j) acc[i][j] = 0.0;

  for (int i0 = 0; i0 < IN1; i0 += 4) {
    {
      int e = threadIdx.x;
      int bb = e & 63, ii = e >> 6;
      double v = xnT[(size_t)(i0 + ii) * BATCH + b0 + bb];
      double t0 = 1.0, t1 = v;
      lbas[ii][bb][0] = t0;
      lbas[ii][bb][1] = t1;
#pragma unroll
      for (int d = 2; d < NB; ++d) {
        double t2 = 2.0 * v * t1 - t0;
        lbas[ii][bb][d] = t2;
        t0 = t1; t1 = t2;
      }
    }
    for (int e = threadIdx.x; e < 64 * 36; e += 256) {
      int oo = e / 36;
      int r  = e - oo * 36;
      int ii = r / NB;
      int d  = r - ii * NB;
      lcf[ii][d][oo] =
          (double)cf[(size_t)(o0 + oo) * K1 + (size_t)(i0 + ii) * NB + d];
    }
    __syncthreads();
#pragma unroll
    for (int ii = 0; ii < 4; ++ii) {
#pragma unroll
      for (int d = 0; d < NB; ++d) {
        double bs[4], cv[4];
#pragma unroll
        for (int r = 0; r < 4; ++r) bs[r] = lbas[ii][tx + 16 * r][d];
#pragma unroll
        for (int r = 0; r < 4; ++r) cv[r] = lcf[ii][d][ty + 16 * r];
#pragma unroll
        for (int ro = 0; ro < 4; ++ro)
#pragma unroll
          for (int rb = 0; rb < 4; ++rb)
            acc[rb][ro] = fma(bs[rb], cv[ro], acc[rb][ro]);
      }
    }
    __syncthreads();
  }
#pragma unroll
  for (int ro = 0; ro < 4; ++ro)
#pragma unroll
    for (int rb = 0; rb < 4; ++rb)
      h1[(size_t)(o0 + ty + 16 * ro) * BATCH + b0 + tx + 16 * rb] = acc[rb][ro];
}

// ---------------- BN stats per feature: A*h_raw + C >= 2.0 is the spike ----
__global__ __launch_bounds__(256)
void k_bnstats(const double* __restrict__ h, const float* __restrict__ scale,
               const float* __restrict__ gamma, const float* __restrict__ beta,
               double* __restrict__ AC, int batch) {
  const int f = blockIdx.x;
  const double* row = h + (size_t)f * batch;
  double s1 = 0.0, s2 = 0.0;
  for (int b = threadIdx.x; b < batch; b += 256) {
    double v = row[b];
    s1 += v;
    s2 = fma(v, v, s2);
  }
#pragma unroll
  for (int off = 32; off > 0; off >>= 1) {
    s1 += __shfl_down(s1, off, 64);
    s2 += __shfl_down(s2, off, 64);
  }
  __shared__ double red[8];
  const int wid = threadIdx.x >> 6;
  if ((threadIdx.x & 63) == 0) { red[wid] = s1; red[4 + wid] = s2; }
  __syncthreads();
  if (threadIdx.x == 0) {
    double S1 = red[0] + red[1] + red[2] + red[3];
    double S2 = red[4] + red[5] + red[6] + red[7];
    double m1 = S1 / batch;
    double m2 = S2 / batch;
    double sc = (double)scale[f], g = (double)gamma[f], be = (double)beta[f];
    double var = sc * sc * (m2 - m1 * m1);
    double inv = 1.0 / sqrt(var + 1e-5);
    double A = g * sc * inv;
    double C = be - g * sc * m1 * inv;
    AC[2 * f] = A;
    AC[2 * f + 1] = C;
  }
}

// ---------------- spike + transpose: s[b][f], sT[f][b] --------------------
__global__ __launch_bounds__(256)
void k_spike_tr(const double* __restrict__ h, const double* __restrict__ AC,
                float* __restrict__ s, float* __restrict__ sT, int batch,
                int F) {
  __shared__ float tile[64][65];
  __shared__ double lA[64], lC[64];
  const int b0 = blockIdx.x * 64;
  const int f0 = blockIdx.y * 64;
  const int t = threadIdx.x;
  if (t < 64) { lA[t] = AC[2 * (f0 + t)]; lC[t] = AC[2 * (f0 + t) + 1]; }
  __syncthreads();
  const int tx = t & 63, tw = t >> 6;
  for (int fo = tw; fo < 64; fo += 4) {
    double v = h[(size_t)(f0 + fo) * batch + b0 + tx];
    tile[tx][fo] = (fma(lA[fo], v, lC[fo]) >= 2.0) ? 1.0f : 0.0f;
  }
  __syncthreads();
  for (int bo = tw; bo < 64; bo += 4) {
    s[(size_t)(b0 + bo) * F + f0 + tx] = tile[bo][tx];
  }
  for (int fo = tw; fo < 64; fo += 4) {
    sT[(size_t)(f0 + fo) * batch + b0 + tx] = tile[tx][fo];
  }
}

// ---------------- layer-2 precompute: binary-input folding ----------------
__global__ __launch_bounds__(256)
void k_prep2(const float* __restrict__ cf2, double* __restrict__ a2,
             double* __restrict__ c0v) {
  const int o = blockIdx.x;
  double bt[NB], b0a[NB];
  {
    double tt = tanh(0.5);
    bt[0] = 1.0; bt[1] = tt;
    b0a[0] = 1.0; b0a[1] = 0.0;
#pragma unroll
    for (int d = 2; d < NB; ++d) {
      bt[d] = 2.0 * tt * bt[d - 1] - bt[d - 2];
      b0a[d] = -b0a[d - 2];
    }
  }
  double cp = 0.0;
  for (int i = threadIdx.x; i < HID1; i += 256) {
    const float* c = cf2 + ((size_t)o * HID1 + i) * NB;
    double av = 0.0, cv = 0.0;
#pragma unroll
    for (int d = 0; d < NB; ++d) {
      double cd = (double)c[d];
      av = fma(bt[d] - b0a[d], cd, av);
      cv = fma(b0a[d], cd, cv);
    }
    a2[(size_t)o * HID1 + i] = av;
    cp += cv;
  }
#pragma unroll
  for (int off = 32; off > 0; off >>= 1) cp += __shfl_down(cp, off, 64);
  __shared__ double red[4];
  if ((threadIdx.x & 63) == 0) red[threadIdx.x >> 6] = cp;
  __syncthreads();
  if (threadIdx.x == 0) c0v[o] = red[0] + red[1] + red[2] + red[3];
}

// ---------------- GEMM2 via f64 MFMA, 2-phase pipelined -------------------
// h2[o][b] = c0[o] + sum_i s1[b][i]*a2[o][i].  Tile 64o x 32b, K-chunk 32.
__global__ __launch_bounds__(256)
void k_gemm2_mfma(const float* __restrict__ s1T, const double* __restrict__ a2,
                  const double* __restrict__ c0v, const int* __restrict__ flag,
                  double* __restrict__ h2) {
  const int fl = flag[0];
  if (fl >= 16) return;
  const int ao = fl >> 3, bo = (fl >> 2) & 1, dopt = fl & 3;
  __shared__ double lA[2][32][67];  // a2 tile  34304 B
  __shared__ float  lB[2][32][40];  // s1T tile 10240 B
  const int tid  = threadIdx.x;
  const int lane = tid & 63;
  const int w    = tid >> 6;
  const int wo   = (w & 1) * 32;
  const int wb   = (w >> 1) * 16;
  const int o0   = blockIdx.y * 64;
  const int b0   = blockIdx.x * 32;
  const int l15  = lane & 15;
  const int l4   = lane >> 4;
  const int am = ao ? (lane >> 2) : l15;
  const int ak = ao ? (lane & 3)  : l4;
  const int bn = bo ? (lane >> 2) : l15;
  const int bk = bo ? (lane & 3)  : l4;
  const int srA = tid >> 2, skA = (tid & 3) * 8;   // A: 4 thr/o-row, 8 k
  const int srB = tid >> 3, scB = (tid & 7) * 4;   // B: 8 thr/k-row, 4 b

  double4v acc[2];
  acc[0] = double4v{0.0, 0.0, 0.0, 0.0};
  acc[1] = double4v{0.0, 0.0, 0.0, 0.0};

  const double* Abase = a2 + (size_t)(o0 + srA) * HID1 + skA;
  const float*  Bbase = s1T + b0 + scB;
  double ar[8];
  float4 br;
#pragma unroll
  for (int q = 0; q < 8; ++q) ar[q] = Abase[q];
  br = *(const float4*)(Bbase + (size_t)srB * BATCH);

  int cur = 0;
  for (int t = 0; t < HID1 / 32; ++t) {
#pragma unroll
    for (int q = 0; q < 8; ++q) lA[cur][skA + q][srA] = ar[q];
    *(float4*)&lB[cur][srB][scB] = br;
    __syncthreads();
    if (t < HID1 / 32 - 1) {
      const int i0 = (t + 1) * 32;
#pragma unroll
      for (int q = 0; q < 8; ++q) ar[q] = Abase[i0 + q];
      br = *(const float4*)(Bbase + (size_t)(i0 + srB) * BATCH);
    }
    __builtin_amdgcn_s_setprio(1);
#pragma unroll
    for (int k4 = 0; k4 < 8; ++k4) {
      double a[2], b;
#pragma unroll
      for (int m = 0; m < 2; ++m)
        a[m] = lA[cur][k4 * 4 + ak][wo + m * 16 + am];
      b = (double)lB[cur][k4 * 4 + bk][wb + bn];
#pragma unroll
      for (int m = 0; m < 2; ++m)
        acc[m] = __builtin_amdgcn_mfma_f64_16x16x4f64(a[m], b, acc[m], 0, 0, 0);
    }
    __builtin_amdgcn_s_setprio(0);
    cur ^= 1;
  }
#pragma unroll
  for (int m = 0; m < 2; ++m) {
    const int ob = o0 + wo + m * 16;
    const int bb = b0 + wb;
    if (dopt == 0) {
      int o = ob + 4 * l4, b = bb + l15;
#pragma unroll
      for (int j = 0; j < 4; ++j)
        h2[(size_t)(o + j) * BATCH + b] = acc[m][j] + c0v[o + j];
    } else if (dopt == 1) {
      int o = ob + l15, b = bb + 4 * l4;
      double c0 = c0v[o];
#pragma unroll
      for (int j = 0; j < 4; ++j)
        h2[(size_t)o * BATCH + b + j] = acc[m][j] + c0;
    } else if (dopt == 2) {
      int o = ob + l4, b = bb + l15;
#pragma unroll
      for (int j = 0; j < 4; ++j)
        h2[(size_t)(o + 4 * j) * BATCH + b] = acc[m][j] + c0v[o + 4 * j];
    } else {
      int o = ob + l15, b = bb + l4;
      double c0 = c0v[o];
#pragma unroll
      for (int j = 0; j < 4; ++j)
        h2[(size_t)o * BATCH + b + 4 * j] = acc[m][j] + c0;
    }
  }
}

// ---------------- GEMM2 VALU fallback (proven; runs iff flag==16) ---------
__global__ __launch_bounds__(256)
void k_gemm2_valu(const float* __restrict__ s1, const double* __restrict__ a2,
                  const double* __restrict__ c0v, const int* __restrict__ flag,
                  double* __restrict__ h2) {
  if (flag[0] != 16) return;
  __shared__ double ls[16][64];
  __shared__ double la[16][32];
  const int tx = threadIdx.x & 15;
  const int ty = threadIdx.x >> 4;
  const int b0 = blockIdx.x * 64;
  const int o0 = blockIdx.y * 32;
  double acc[4][2] = {{0, 0}, {0, 0}, {0, 0}, {0, 0}};
  for (int i0 = 0; i0 < HID1; i0 += 16) {
    for (int e = threadIdx.x; e < 64 * 16; e += 256) {
      int bb = e & 63, ii = e >> 6;
      ls[ii][bb] = (double)s1[(size_t)(b0 + bb) * HID1 + i0 + ii];
    }
    for (int e = threadIdx.x; e < 32 * 16; e += 256) {
      int oo = e & 31, ii = e >> 5;
      la[ii][oo] = a2[(size_t)(o0 + oo) * HID1 + i0 + ii];
    }
    __syncthreads();
#pragma unroll
    for (int ii = 0; ii < 16; ++ii) {
      double sv[4], av[2];
#pragma unroll
      for (int r = 0; r < 4; ++r) sv[r] = ls[ii][tx + 16 * r];
      av[0] = la[ii][ty];
      av[1] = la[ii][ty + 16];
#pragma unroll
      for (int ro = 0; ro < 2; ++ro)
#pragma unroll
        for (int rb = 0; rb < 4; ++rb)
          acc[rb][ro] = fma(sv[rb], av[ro], acc[rb][ro]);
    }
    __syncthreads();
  }
#pragma unroll
  for (int ro = 0; ro < 2; ++ro) {
    double c0 = c0v[o0 + ty + 16 * ro];
#pragma unroll
    for (int rb = 0; rb < 4; ++rb)
      h2[(size_t)(o0 + ty + 16 * ro) * BATCH + b0 + tx + 16 * rb] =
          acc[rb][ro] + c0;
  }
}

// ---------------- GEMM3 (f32): out[b][n] = bias[n] + sum_k s2[b][k]*w[n][k] -
__global__ __launch_bounds__(256)
void k_gemm3(const float* __restrict__ s2, const float* __restrict__ w,
             const float* __restrict__ bias, float* __restrict__ out) {
  __shared__ float lsS[32][64];
  __shared__ float lw[32][64];
  const int tx = threadIdx.x & 15;  // n
  const int ty = threadIdx.x >> 4;  // b
  const int b0 = blockIdx.x * 64;
  const int n0 = blockIdx.y * 64;
  float acc[4][4];
#pragma unroll
  for (int i = 0; i < 4; ++i)
#pragma unroll
    for (int j = 0; j < 4; ++j) acc[i][j] = 0.0f;
  for (int k0 = 0; k0 < HID2; k0 += 32) {
    for (int e = threadIdx.x; e < 64 * 32; e += 256) {
      int bb = e & 63, kk = e >> 6;
      lsS[kk][bb] = s2[(size_t)(b0 + bb) * HID2 + k0 + kk];
    }
    for (int e = threadIdx.x; e < 64 * 32; e += 256) {
      int nn = e & 63, kk = e >> 6;
      int n = n0 + nn;
      lw[kk][nn] = (n < NCLS) ? w[(size_t)n * HID2 + k0 + kk] : 0.0f;
    }
    __syncthreads();
#pragma unroll
    for (int kk = 0; kk < 32; ++kk) {
      float sv[4], wv[4];
#pragma unroll
      for (int r = 0; r < 4; ++r) sv[r] = lsS[kk][ty + 16 * r];
#pragma unroll
      for (int r = 0; r < 4; ++r) wv[r] = lw[kk][tx + 16 * r];
#pragma unroll
      for (int rb = 0; rb < 4; ++rb)
#pragma unroll
        for (int rn = 0; rn < 4; ++rn)
          acc[rb][rn] = fmaf(sv[rb], wv[rn], acc[rb][rn]);
    }
    __syncthreads();
  }
#pragma unroll
  for (int rn = 0; rn < 4; ++rn) {
    int n = n0 + tx + 16 * rn;
    if (n < NCLS) {
      float bv = bias[n];
#pragma unroll
      for (int rb = 0; rb < 4; ++rb)
        out[(size_t)(b0 + ty + 16 * rb) * NCLS + n] = acc[rb][rn] + bv;
    }
  }
}

extern "C" void kernel_launch(void* const* d_in, const int* in_sizes, int n_in,
                              void* d_out, int out_size, void* d_ws,
                              size_t ws_size, hipStream_t stream) {
  (void)in_sizes; (void)n_in; (void)out_size; (void)ws_size;
  const float* x       = (const float*)d_in[0];
  const float* coeffs1 = (const float*)d_in[1];
  const float* scale1  = (const float*)d_in[2];
  const float* gamma1  = (const float*)d_in[3];
  const float* beta1   = (const float*)d_in[4];
  const float* coeffs2 = (const float*)d_in[5];
  const float* scale2  = (const float*)d_in[6];
  const float* gamma2  = (const float*)d_in[7];
  const float* beta2   = (const float*)d_in[8];
  const float* w       = (const float*)d_in[9];
  const float* bias    = (const float*)d_in[10];

  float* out = (float*)d_out;
  float* s1  = out + (size_t)BATCH * NCLS;
  float* s2  = s1 + (size_t)BATCH * HID1;

  char* ws = (char*)d_ws;
  int*    flag = (int*)ws;    ws += 16;
  double* xnT  = (double*)ws; ws += (size_t)IN1 * BATCH * 8;   // reused: s1T
  double* h1   = (double*)ws; ws += (size_t)HID1 * BATCH * 8;  // reused: s2T
  double* AC1  = (double*)ws; ws += (size_t)HID1 * 2 * 8;
  double* a2   = (double*)ws; ws += (size_t)HID2 * HID1 * 8;
  double* c0v  = (double*)ws; ws += (size_t)HID2 * 8;
  double* h2   = (double*)ws; ws += (size_t)HID2 * BATCH * 8;
  double* AC2  = (double*)ws; ws += (size_t)HID2 * 2 * 8;
  double* c1c  = (double*)ws; ws += (size_t)HID1 * 8;

  float* s1T = (float*)xnT;  // 8 MB region, xnT dead after gemm1
  float* s2T = (float*)h1;   // h1 dead after spike_tr1 (unused output)

  k_xnT<<<dim3(IN1 / 32, BATCH / 32), 256, 0, stream>>>(x, xnT);
  k_probe<<<1, 64, 0, stream>>>(flag);
  k_prep1<<<HID1, 64, 0, stream>>>(coeffs1, c1c);
  k_prep2<<<HID2, 256, 0, stream>>>(coeffs2, a2, c0v);
  k_gemm1_mfma<<<dim3(BATCH / 32, HID1 / 128), 256, 0, stream>>>(
      xnT, coeffs1, c1c, flag, h1);
  k_gemm1_valu<<<dim3(BATCH / 64, HID1 / 64), 256, 0, stream>>>(xnT, coeffs1,
                                                                flag, h1);
  k_bnstats<<<HID1, 256, 0, stream>>>(h1, scale1, gamma1, beta1, AC1, BATCH);
  k_spike_tr<<<dim3(BATCH / 64, HID1 / 64), 256, 0, stream>>>(h1, AC1, s1, s1T,
                                                              BATCH, HID1);
  k_gemm2_mfma<<<dim3(BATCH / 32, HID2 / 64), 256, 0, stream>>>(s1T, a2, c0v,
                                                                flag, h2);
  k_gemm2_valu<<<dim3(BATCH / 64, HID2 / 32), 256, 0, stream>>>(s1, a2, c0v,
                                                                flag, h2);
  k_bnstats<<<HID2, 256, 0, stream>>>(h2, scale2, gamma2, beta2, AC2, BATCH);
  k_spike_tr<<<dim3(BATCH / 64, HID2 / 64), 256, 0, stream>>>(h2, AC2, s2, s2T,
                                                              BATCH, HID2);
  k_gemm3<<<dim3(BATCH / 64, 1024 / 64), 256, 0, stream>>>(s2, w, bias, out);
}